// Round 8
// baseline (311.027 us; speedup 1.0000x reference)
//
#include <hip/hip_runtime.h>
#include <cstdint>
#include <cstddef>

#define H 8
#define DHID 128
#define BM 64            // rows per MFMA block
#define LDST 136         // padded LDS row stride (bf16 elems)
#define NEG_SLOPE 0.2f
#define GN_EPS 1e-5f

#define SCAN_T 256
#define SCAN_I 4         // 1024 elements per scan block

typedef __attribute__((ext_vector_type(8))) short short8;
typedef __attribute__((ext_vector_type(4))) float f32x4;

__device__ __forceinline__ void atomAddF(float* p, float v) {
    __hip_atomic_fetch_add(p, v, __ATOMIC_RELAXED, __HIP_MEMORY_SCOPE_AGENT);
}
__device__ __forceinline__ unsigned short f2bf(float f) {
    uint32_t u = __float_as_uint(f);
    uint32_t r = (u + 0x7FFFu + ((u >> 16) & 1u)) >> 16;
    return (unsigned short)r;
}
__device__ __forceinline__ float bflo(uint32_t v) { return __uint_as_float(v << 16); }
__device__ __forceinline__ float bfhi(uint32_t v) { return __uint_as_float(v & 0xFFFF0000u); }

// ---------------------------------------------------------------------------
// K1: prep (pack weights -> MFMA B-frags with attention fold inline, misc init)
//     ∥ deg_hist (both edge types + self loops); hist also records each edge's
//     rank within its dst segment (atomicAdd return) -> rank[], enabling an
//     atomic-free scatter later.
// ---------------------------------------------------------------------------
struct PrepHist {
    const float *Wlp, *Wsc, *Wla, *Wsw, *W2p;
    const float *Wdw, *adw, *asc_, *Wdc, *adc_, *asw_;
    unsigned short *WlinP_p, *WsrcP_c, *WlinP_a, *WsrcP_w, *W2P_p, *VscP_p, *VscP_a;
    const float *bw, *bc, *gnb_a, *W2a, *b2a;
    float *bsum, *row_a, *colsum, *colsumsq;
    unsigned short *xs_w_ph, *xs_c_ph;
    float *as_w_ph, *as_c_ph;
    const int *dst_w, *dst_c;
    int *deg, *rank;
    int Ew, nself_w, Ec, nself_c, Np, HB0;
};

__global__ void prep_hist(PrepHist a) {
    int b = blockIdx.x, t = threadIdx.x;
    if (b >= a.HB0) {
        int i = (b - a.HB0) * 256 + t;
        int tw = a.Ew + a.nself_w;
        if (i < tw) {
            int d = (i < a.Ew) ? a.dst_w[i] : (i - a.Ew);
            a.rank[i] = atomicAdd(&a.deg[d], 1);
        } else {
            int j = i - tw;
            if (j < a.Ec + a.nself_c) {
                int d = (j < a.Ec) ? a.dst_c[j] : (j - a.Ec);
                a.rank[i] = atomicAdd(&a.deg[a.Np + d], 1);
            }
        }
        return;
    }
    if (b == 56) {
        if (t < 128) {
            a.bsum[t] = a.bw[t] + a.bc[t];
            float acc = a.b2a[t];
            for (int k = 0; k < DHID; ++k) acc += a.gnb_a[k] * a.W2a[k * DHID + t];
            a.row_a[t] = acc;
            a.colsum[t] = 0.f;
            a.colsumsq[t] = 0.f;
            a.xs_w_ph[t] = 0;
            a.xs_c_ph[t] = 0;
        } else if (t < 136) a.as_w_ph[t - 128] = -1e30f;
        else if (t < 144) a.as_c_ph[t - 136] = -1e30f;
        return;
    }
    int j = b >> 3;
    int idx = (b & 7) * 256 + t;
    int lane = idx & 63, kk = (idx >> 6) & 3, nt = idx >> 8;
    int col = nt * 16 + (lane & 15);
    int k0 = kk * 32 + ((lane >> 4) << 3);
    if (j < 5) {
        const float* W = j == 0 ? a.Wlp : j == 1 ? a.Wsc : j == 2 ? a.Wla : j == 3 ? a.Wsw : a.W2p;
        unsigned short* out = j == 0 ? a.WlinP_p : j == 1 ? a.WsrcP_c : j == 2 ? a.WlinP_a
                              : j == 3 ? a.WsrcP_w : a.W2P_p;
        for (int i = 0; i < 8; ++i) out[idx * 8 + i] = f2bf(W[(k0 + i) * DHID + col]);
    } else if (j == 5) {
        if (idx >= 2 * 256) return;
        const float *W = nullptr, *A = nullptr;
        int h = col & 7;
        if (col < 24) {
            int which = col >> 3;
            W = which == 0 ? a.Wdw : which == 1 ? a.Wsc : a.Wdc;
            A = which == 0 ? a.adw : which == 1 ? a.asc_ : a.adc_;
        }
        for (int i = 0; i < 8; ++i) {
            float v = 0.f;
            if (W)
                for (int c = 0; c < 16; ++c) v += W[(k0 + i) * DHID + h * 16 + c] * A[h * 16 + c];
            a.VscP_p[idx * 8 + i] = f2bf(v);
        }
    } else {
        if (idx >= 256) return;
        int h = col & 7;
        for (int i = 0; i < 8; ++i) {
            float v = 0.f;
            if (col < 8)
                for (int c = 0; c < 16; ++c)
                    v += a.Wsw[(k0 + i) * DHID + h * 16 + c] * a.asw_[h * 16 + c];
            a.VscP_a[idx * 8 + i] = f2bf(v);
        }
    }
}

// ---------------------------------------------------------------------------
// Exclusive scan pass 1. pad!=0 rounds each value up to multiple of 4.
// ---------------------------------------------------------------------------
__global__ void scan1(const int* __restrict__ in, int n, int* __restrict__ out,
                      int* __restrict__ bsums, int pad, int* __restrict__ totalOut) {
    __shared__ int sh[SCAN_T];
    int t = threadIdx.x;
    long base = (long)blockIdx.x * SCAN_T * SCAN_I;
    int v[SCAN_I];
    int s = 0;
#pragma unroll
    for (int j = 0; j < SCAN_I; ++j) {
        long idx = base + (long)t * SCAN_I + j;
        int x = (idx < n) ? in[idx] : 0;
        if (pad) x = (x + 3) & ~3;
        v[j] = x;
        s += x;
    }
    sh[t] = s;
    __syncthreads();
    for (int off = 1; off < SCAN_T; off <<= 1) {
        int x = (t >= off) ? sh[t - off] : 0;
        __syncthreads();
        sh[t] += x;
        __syncthreads();
    }
    int run = sh[t] - s;
#pragma unroll
    for (int j = 0; j < SCAN_I; ++j) {
        long idx = base + (long)t * SCAN_I + j;
        if (idx < n) out[idx] = run;
        run += v[j];
    }
    if (t == SCAN_T - 1) {
        bsums[blockIdx.x] = sh[SCAN_T - 1];
        if (totalOut) *totalOut = sh[SCAN_T - 1];
    }
}

// ---------------------------------------------------------------------------
// scan3 (off_raw+bs1 -> off2) ∥ prefill of srcu with phantom ids.
// ---------------------------------------------------------------------------
__global__ void scan3_prefill(const int* __restrict__ off_raw, const int* __restrict__ bs1,
                              int n2, int* __restrict__ off2,
                              int Np, int Na, int maxTot, int* __restrict__ srcu) {
    int i = blockIdx.x * 256 + threadIdx.x;
    if (i < n2) off2[i] = off_raw[i] + bs1[i / (SCAN_T * SCAN_I)];
    int mid = off_raw[Np] + bs1[Np / (SCAN_T * SCAN_I)];
    long stride = (long)gridDim.x * 256;
    for (long k = i; k < maxTot; k += stride) srcu[k] = (k < (long)mid) ? Na : Np;
}

// ---------------------------------------------------------------------------
// MFMA projection body (paper NSC=2 / author NSC=1)
// ---------------------------------------------------------------------------
template <int NSC>
__device__ void proj_body(unsigned short* xt, int bid,
                          const float* __restrict__ x, int nrows,
                          const unsigned short* __restrict__ WlinP, const float* __restrict__ blin,
                          const unsigned short* __restrict__ WsrcP,
                          const unsigned short* __restrict__ VscP,
                          unsigned short* __restrict__ xs,
                          float* __restrict__ a0, float* __restrict__ a1, float* __restrict__ a2) {
    int t = threadIdx.x;
    int lane = t & 63, w = t >> 6;
    long row0 = (long)bid * BM;
    for (int it = 0; it < 16; ++it) {
        int idx2 = t + it * 256;
        int r = idx2 >> 6, cp = idx2 & 63;
        long gr = row0 + r;
        float v0 = 0.f, v1 = 0.f;
        if (gr < nrows) { v0 = x[gr * DHID + 2 * cp]; v1 = x[gr * DHID + 2 * cp + 1]; }
        uint32_t pk = (uint32_t)f2bf(v0) | ((uint32_t)f2bf(v1) << 16);
        *reinterpret_cast<uint32_t*>(&xt[r * LDST + 2 * cp]) = pk;
    }
    __syncthreads();
    int arow = w * 16 + (lane & 15);
    int koff = (lane >> 4) << 3;
    short8 af[4];
#pragma unroll
    for (int kk = 0; kk < 4; ++kk)
        af[kk] = *reinterpret_cast<const short8*>(&xt[arow * LDST + kk * 32 + koff]);
    const short8* Bl = reinterpret_cast<const short8*>(WlinP);
    f32x4 acc[8];
#pragma unroll
    for (int nt = 0; nt < 8; ++nt) {
        f32x4 a = {0.f, 0.f, 0.f, 0.f};
#pragma unroll
        for (int kk = 0; kk < 4; ++kk)
            a = __builtin_amdgcn_mfma_f32_16x16x32_bf16(af[kk], Bl[(nt * 4 + kk) * 64 + lane], a, 0, 0, 0);
        acc[nt] = a;
    }
    __syncthreads();
    int orow = w * 16 + ((lane >> 4) << 2);
    int ccol = lane & 15;
#pragma unroll
    for (int nt = 0; nt < 8; ++nt) {
        float b = blin[nt * 16 + ccol];
#pragma unroll
        for (int r = 0; r < 4; ++r) {
            float e = fmaxf(acc[nt][r] + b, 0.f);
            xt[(orow + r) * LDST + nt * 16 + ccol] = f2bf(e);
        }
    }
    __syncthreads();
#pragma unroll
    for (int kk = 0; kk < 4; ++kk)
        af[kk] = *reinterpret_cast<const short8*>(&xt[arow * LDST + kk * 32 + koff]);
    const short8* Bs = reinterpret_cast<const short8*>(WsrcP);
#pragma unroll
    for (int nt = 0; nt < 8; ++nt) {
        f32x4 a = {0.f, 0.f, 0.f, 0.f};
#pragma unroll
        for (int kk = 0; kk < 4; ++kk)
            a = __builtin_amdgcn_mfma_f32_16x16x32_bf16(af[kk], Bs[(nt * 4 + kk) * 64 + lane], a, 0, 0, 0);
        acc[nt] = a;
    }
    const short8* Bv = reinterpret_cast<const short8*>(VscP);
    f32x4 sacc0 = {0.f, 0.f, 0.f, 0.f}, sacc1 = {0.f, 0.f, 0.f, 0.f};
#pragma unroll
    for (int kk = 0; kk < 4; ++kk)
        sacc0 = __builtin_amdgcn_mfma_f32_16x16x32_bf16(af[kk], Bv[kk * 64 + lane], sacc0, 0, 0, 0);
    if (NSC > 1) {
#pragma unroll
        for (int kk = 0; kk < 4; ++kk)
            sacc1 = __builtin_amdgcn_mfma_f32_16x16x32_bf16(af[kk], Bv[(4 + kk) * 64 + lane], sacc1, 0, 0, 0);
    }
#pragma unroll
    for (int nt = 0; nt < 8; ++nt) {
#pragma unroll
        for (int r = 0; r < 4; ++r) {
            long gr = row0 + orow + r;
            if (gr < nrows) xs[gr * DHID + nt * 16 + ccol] = f2bf(acc[nt][r]);
        }
    }
#pragma unroll
    for (int st = 0; st < NSC; ++st) {
        int scol = st * 16 + ccol;
        int h = scol & 7, which = scol >> 3;
        float* ap = which == 0 ? a0 : which == 1 ? a1 : which == 2 ? a2 : nullptr;
        if (ap) {
            f32x4 s = st == 0 ? sacc0 : sacc1;
#pragma unroll
            for (int r = 0; r < 4; ++r) {
                long gr = row0 + orow + r;
                if (gr < nrows) ap[gr * H + h] = s[r];
            }
        }
    }
}

// ---------------------------------------------------------------------------
// K4 MEGA: proj_paper ∥ proj_author ∥ atomic-free csr_scatter.
// Roles interleaved Bresenham-style so proj and scatter are co-resident.
// ---------------------------------------------------------------------------
struct MegaArgs {
    const float* x_p; int Np;
    const unsigned short* WlinP_p; const float* blp;
    const unsigned short* WsrcP_c; const unsigned short* VscP_p;
    unsigned short* xs_c; float *a_d_w, *a_s_c, *a_d_c;
    const float* x_a; int Na;
    const unsigned short* WlinP_a; const float* bla;
    const unsigned short* WsrcP_w; const unsigned short* VscP_a;
    unsigned short* xs_w; float* a_s_w;
    const int *src_w, *dst_w, *src_c, *dst_c;
    int Ew, nself_w, Ec, nself_c;
    const int *off2, *rank;
    int* srcu;
    int PB, AB;
};

__global__ __launch_bounds__(256) void mega(MegaArgs a) {
    __shared__ unsigned short xt[BM * LDST];
    int b = blockIdx.x;
    int G = gridDim.x;
    int nP = a.PB + a.AB;
    long fb  = (long)b * nP / G;
    long fb1 = (long)(b + 1) * nP / G;
    if (fb1 > fb) {
        int pb = (int)fb;
        if (pb < a.PB)
            proj_body<2>(xt, pb, a.x_p, a.Np, a.WlinP_p, a.blp, a.WsrcP_c, a.VscP_p,
                         a.xs_c, a.a_d_w, a.a_s_c, a.a_d_c);
        else
            proj_body<1>(xt, pb - a.PB, a.x_a, a.Na, a.WlinP_a, a.bla, a.WsrcP_w, a.VscP_a,
                         a.xs_w, a.a_s_w, nullptr, nullptr);
        return;
    }
    int sb = b - (int)fb;          // scatter block index
    int i = sb * 256 + threadIdx.x;
    int tw = a.Ew + a.nself_w;
    int s, di;
    if (i < tw) {
        if (i < a.Ew) { s = a.src_w[i]; di = a.dst_w[i]; } else { s = di = i - a.Ew; }
    } else {
        int j = i - tw;
        if (j >= a.Ec + a.nself_c) return;
        if (j < a.Ec) { s = a.src_c[j]; di = a.Np + a.dst_c[j]; }
        else { s = j - a.Ec; di = a.Np + (j - a.Ec); }
    }
    a.srcu[a.off2[di] + a.rank[i]] = s;
}

// ---------------------------------------------------------------------------
// Gather (unchanged)
// ---------------------------------------------------------------------------
__global__ __launch_bounds__(256) void gat_gather(
    const int* __restrict__ off, const int* __restrict__ srcu,
    const float* __restrict__ a_s_w, const float* __restrict__ a_d_w,
    const float* __restrict__ a_s_c, const float* __restrict__ a_d_c,
    const unsigned short* __restrict__ xs_w, const unsigned short* __restrict__ xs_c,
    float* __restrict__ gat, int Np) {
    int l = threadIdx.x & 63;
    int d = blockIdx.x * 4 + (threadIdx.x >> 6);
    if (d >= Np) return;
    int h = l >> 3;
    int iw = off[d], w1 = off[d + 1];
    int ic = off[Np + d], c1 = off[Np + d + 1];
    float adw = a_d_w[(long)d * H + h];
    float adc = a_d_c[(long)d * H + h];
    float denw = 0.f, n0w = 0.f, n1w = 0.f;
    float denc = 0.f, n0c = 0.f, n1c = 0.f;
    while (iw < w1 || ic < c1) {
        bool hw = iw < w1, hc = ic < c1;
        int4 sw, sc;
        if (hw) sw = *reinterpret_cast<const int4*>(srcu + iw);
        if (hc) sc = *reinterpret_cast<const int4*>(srcu + ic);
        float ew[4], ec[4];
        uint32_t vw[4], vc[4];
        if (hw) {
            ew[0] = a_s_w[(long)sw.x * H + h];
            ew[1] = a_s_w[(long)sw.y * H + h];
            ew[2] = a_s_w[(long)sw.z * H + h];
            ew[3] = a_s_w[(long)sw.w * H + h];
            vw[0] = *reinterpret_cast<const uint32_t*>(xs_w + (long)sw.x * DHID + 2 * l);
            vw[1] = *reinterpret_cast<const uint32_t*>(xs_w + (long)sw.y * DHID + 2 * l);
            vw[2] = *reinterpret_cast<const uint32_t*>(xs_w + (long)sw.z * DHID + 2 * l);
            vw[3] = *reinterpret_cast<const uint32_t*>(xs_w + (long)sw.w * DHID + 2 * l);
        }
        if (hc) {
            ec[0] = a_s_c[(long)sc.x * H + h];
            ec[1] = a_s_c[(long)sc.y * H + h];
            ec[2] = a_s_c[(long)sc.z * H + h];
            ec[3] = a_s_c[(long)sc.w * H + h];
            vc[0] = *reinterpret_cast<const uint32_t*>(xs_c + (long)sc.x * DHID + 2 * l);
            vc[1] = *reinterpret_cast<const uint32_t*>(xs_c + (long)sc.y * DHID + 2 * l);
            vc[2] = *reinterpret_cast<const uint32_t*>(xs_c + (long)sc.z * DHID + 2 * l);
            vc[3] = *reinterpret_cast<const uint32_t*>(xs_c + (long)sc.w * DHID + 2 * l);
        }
        if (hw) {
#pragma unroll
            for (int j = 0; j < 4; ++j) {
                float e = ew[j] + adw;
                e = e > 0.f ? e : NEG_SLOPE * e;
                float p = __expf(e);
                denw += p;
                n0w += p * bflo(vw[j]);
                n1w += p * bfhi(vw[j]);
            }
            iw += 4;
        }
        if (hc) {
#pragma unroll
            for (int j = 0; j < 4; ++j) {
                float e = ec[j] + adc;
                e = e > 0.f ? e : NEG_SLOPE * e;
                float p = __expf(e);
                denc += p;
                n0c += p * bflo(vc[j]);
                n1c += p * bfhi(vc[j]);
            }
            ic += 4;
        }
    }
    float rw = 1.f / (denw + 1e-16f);
    float rc = 1.f / (denc + 1e-16f);
    float2 o;
    o.x = n0w * rw + n0c * rc;
    o.y = n1w * rw + n1c * rc;
    *reinterpret_cast<float2*>(&gat[(long)d * DHID + 2 * l]) = o;
}

// ---------------------------------------------------------------------------
// GraphNorm reduction
// ---------------------------------------------------------------------------
#define GN_ROWS 128
__global__ void gn_reduce(const float* __restrict__ gat, const float* __restrict__ bsum,
                          float* __restrict__ colsum, float* __restrict__ colsumsq, int Np) {
    int t = threadIdx.x;
    long r0 = (long)blockIdx.x * GN_ROWS;
    long r1 = min(r0 + GN_ROWS, (long)Np);
    float b = bsum[t], s1 = 0.f, s2 = 0.f;
    for (long r = r0; r < r1; ++r) {
        float xv = gat[r * DHID + t] + b;
        s1 += xv;
        s2 += xv * xv;
    }
    atomAddF(colsum + t, s1);
    atomAddF(colsumsq + t, s2);
}

// ---------------------------------------------------------------------------
// K7: final_mfma (paper gnorm + @W2 + b2) ∥ author broadcast fill
// ---------------------------------------------------------------------------
__global__ __launch_bounds__(256) void final_fill(
    const float* __restrict__ gat, const float* __restrict__ bsum,
    const float* __restrict__ colsum, const float* __restrict__ colsumsq,
    const float* __restrict__ gnw, const float* __restrict__ gnb,
    const float* __restrict__ gnm,
    const unsigned short* __restrict__ W2P, const float* __restrict__ b2,
    float* __restrict__ out, int Np, int FB,
    const float* __restrict__ row_a, float4* __restrict__ outa, long n4) {
    __shared__ unsigned short xt[BM * LDST];
    __shared__ float cscale[DHID], cshift[DHID];
    int b = blockIdx.x;
    int t = threadIdx.x;
    if (b >= FB) {
        long i = (long)(b - FB) * 256 + t;
        long stride = (long)(gridDim.x - FB) * 256;
        const float4* r4 = reinterpret_cast<const float4*>(row_a);
        for (; i < n4; i += stride) outa[i] = r4[i & 31];
        return;
    }
    int lane = t & 63, w = t >> 6;
    long row0 = (long)b * BM;
    if (t < DHID) {
        float invN = 1.f / (float)Np;
        float mu = colsum[t] * invN;
        float ms = gnm[t];
        float var = colsumsq[t] * invN - mu * mu * ms * (2.f - ms);
        float sc = gnw[t] * rsqrtf(var + GN_EPS);
        cscale[t] = sc;
        cshift[t] = (bsum[t] - ms * mu) * sc + gnb[t];
    }
    __syncthreads();
    for (int it = 0; it < 16; ++it) {
        int idx2 = t + it * 256;
        int r = idx2 >> 6, cp = idx2 & 63;
        long gr = row0 + r;
        float v0 = 0.f, v1 = 0.f;
        if (gr < Np) {
            v0 = gat[gr * DHID + 2 * cp] * cscale[2 * cp] + cshift[2 * cp];
            v1 = gat[gr * DHID + 2 * cp + 1] * cscale[2 * cp + 1] + cshift[2 * cp + 1];
        }
        uint32_t pk = (uint32_t)f2bf(v0) | ((uint32_t)f2bf(v1) << 16);
        *reinterpret_cast<uint32_t*>(&xt[r * LDST + 2 * cp]) = pk;
    }
    __syncthreads();
    int arow = w * 16 + (lane & 15);
    int koff = (lane >> 4) << 3;
    short8 af[4];
#pragma unroll
    for (int kk = 0; kk < 4; ++kk)
        af[kk] = *reinterpret_cast<const short8*>(&xt[arow * LDST + kk * 32 + koff]);
    const short8* Bw = reinterpret_cast<const short8*>(W2P);
    int orow = w * 16 + ((lane >> 4) << 2);
    int ccol = lane & 15;
#pragma unroll
    for (int nt = 0; nt < 8; ++nt) {
        f32x4 a = {0.f, 0.f, 0.f, 0.f};
#pragma unroll
        for (int kk = 0; kk < 4; ++kk)
            a = __builtin_amdgcn_mfma_f32_16x16x32_bf16(af[kk], Bw[(nt * 4 + kk) * 64 + lane], a, 0, 0, 0);
        float bb = b2[nt * 16 + ccol];
#pragma unroll
        for (int r = 0; r < 4; ++r) {
            long gr = row0 + orow + r;
            if (gr < Np) out[gr * DHID + nt * 16 + ccol] = a[r] + bb;
        }
    }
}

// ---------------------------------------------------------------------------
extern "C" void kernel_launch(void* const* d_in, const int* in_sizes, int n_in,
                              void* d_out, int out_size, void* d_ws, size_t ws_size,
                              hipStream_t stream) {
    const float* x_p   = (const float*)d_in[0];
    const float* x_a   = (const float*)d_in[1];
    const int*   e_w   = (const int*)d_in[2];
    const int*   e_c   = (const int*)d_in[3];
    const float* Wlp   = (const float*)d_in[4];
    const float* blp   = (const float*)d_in[5];
    const float* Wla   = (const float*)d_in[6];
    const float* bla   = (const float*)d_in[7];
    const float* Wsw   = (const float*)d_in[8];
    const float* Wdw   = (const float*)d_in[9];
    const float* asw   = (const float*)d_in[10];
    const float* adw   = (const float*)d_in[11];
    const float* bw    = (const float*)d_in[12];
    const float* Wsc   = (const float*)d_in[13];
    const float* Wdc   = (const float*)d_in[14];
    const float* asc   = (const float*)d_in[15];
    const float* adc   = (const float*)d_in[16];
    const float* bc    = (const float*)d_in[17];
    const float* gnw_p = (const float*)d_in[18];
    const float* gnb_p = (const float*)d_in[19];
    const float* gnm_p = (const float*)d_in[20];
    const float* gnb_a = (const float*)d_in[22];
    const float* W2p   = (const float*)d_in[24];
    const float* b2p   = (const float*)d_in[25];
    const float* W2a   = (const float*)d_in[26];
    const float* b2a   = (const float*)d_in[27];

    int Np = in_sizes[0] / DHID;
    int Na = in_sizes[1] / DHID;
    int Ew = in_sizes[2] / 2;
    int Ec = in_sizes[3] / 2;
    int nself_w = Na < Np ? Na : Np;
    int nself_c = Np;
    int tot_all = (Ew + nself_w) + (Ec + nself_c);
    int maxTot = tot_all + 6 * Np + 8;

    float* ws = (float*)d_ws;
    float* gat   = ws;                                 // Np*128
    float* a_d_w = gat + (size_t)Np * DHID;            // Np*8
    float* a_d_c = a_d_w + (size_t)Np * H;             // Np*8
    float* a_s_w = a_d_c + (size_t)Np * H;             // (Na+1)*8
    float* a_s_c = a_s_w + (size_t)(Na + 1) * H;       // (Np+1)*8
    float* bsum  = a_s_c + (size_t)(Np + 1) * H;       // 128
    float* row_a = bsum + DHID;                        // 128
    float* colsum   = row_a + DHID;                    // 128
    float* colsumsq = colsum + DHID;                   // 128
    int*   deg   = (int*)(colsumsq + DHID);            // 2*Np (memset)
    int* off_raw = deg + 2 * Np;                       // 2*Np
    int* off2    = off_raw + 2 * Np;                   // 2*Np + 1
    int* bs1     = off2 + 2 * Np + 1;                  // 512
    int* bs2     = bs1 + 512;                          // 512
    uintptr_t up = (uintptr_t)(bs2 + 512);
    up = (up + 15) & ~(uintptr_t)15;
    int* srcu = (int*)up;                              // maxTot
    int* rank = srcu + maxTot;                         // tot_all
    unsigned short* xs_w = (unsigned short*)(rank + tot_all);  // (Na+1)*128
    unsigned short* xs_c = xs_w + (size_t)(Na + 1) * DHID;     // (Np+1)*128
    up = (uintptr_t)(xs_c + (size_t)(Np + 1) * DHID);
    up = (up + 15) & ~(uintptr_t)15;
    unsigned short* WlinP_p = (unsigned short*)up;
    unsigned short* WsrcP_c = WlinP_p + 16384;
    unsigned short* WlinP_a = WsrcP_c + 16384;
    unsigned short* WsrcP_w = WlinP_a + 16384;
    unsigned short* W2P_p   = WsrcP_w + 16384;
    unsigned short* VscP_p  = W2P_p + 16384;
    unsigned short* VscP_a  = VscP_p + 4096;

    hipMemsetAsync(deg, 0, 2 * (size_t)Np * sizeof(int), stream);

    int HB = (tot_all + 255) / 256;
    {
        PrepHist pa;
        pa.Wlp = Wlp; pa.Wsc = Wsc; pa.Wla = Wla; pa.Wsw = Wsw; pa.W2p = W2p;
        pa.Wdw = Wdw; pa.adw = adw; pa.asc_ = asc; pa.Wdc = Wdc; pa.adc_ = adc; pa.asw_ = asw;
        pa.WlinP_p = WlinP_p; pa.WsrcP_c = WsrcP_c; pa.WlinP_a = WlinP_a;
        pa.WsrcP_w = WsrcP_w; pa.W2P_p = W2P_p; pa.VscP_p = VscP_p; pa.VscP_a = VscP_a;
        pa.bw = bw; pa.bc = bc; pa.gnb_a = gnb_a; pa.W2a = W2a; pa.b2a = b2a;
        pa.bsum = bsum; pa.row_a = row_a; pa.colsum = colsum; pa.colsumsq = colsumsq;
        pa.xs_w_ph = xs_w + (size_t)Na * DHID;
        pa.xs_c_ph = xs_c + (size_t)Np * DHID;
        pa.as_w_ph = a_s_w + (size_t)Na * H;
        pa.as_c_ph = a_s_c + (size_t)Np * H;
        pa.dst_w = e_w + Ew; pa.dst_c = e_c + Ec;
        pa.deg = deg; pa.rank = rank;
        pa.Ew = Ew; pa.nself_w = nself_w; pa.Ec = Ec; pa.nself_c = nself_c;
        pa.Np = Np; pa.HB0 = 57;
        prep_hist<<<57 + HB, 256, 0, stream>>>(pa);
    }

    int n2 = 2 * Np;
    int nb = (n2 + SCAN_T * SCAN_I - 1) / (SCAN_T * SCAN_I);
    scan1<<<nb, SCAN_T, 0, stream>>>(deg, n2, off_raw, bs1, 1, nullptr);
    scan1<<<1, SCAN_T, 0, stream>>>(bs1, nb, bs1, bs2, 0, off2 + n2);

    scan3_prefill<<<(maxTot + 255) / 256, 256, 0, stream>>>(
        off_raw, bs1, n2, off2, Np, Na, maxTot, srcu);

    {
        MegaArgs ma;
        ma.x_p = x_p; ma.Np = Np; ma.WlinP_p = WlinP_p; ma.blp = blp;
        ma.WsrcP_c = WsrcP_c; ma.VscP_p = VscP_p;
        ma.xs_c = xs_c; ma.a_d_w = a_d_w; ma.a_s_c = a_s_c; ma.a_d_c = a_d_c;
        ma.x_a = x_a; ma.Na = Na; ma.WlinP_a = WlinP_a; ma.bla = bla;
        ma.WsrcP_w = WsrcP_w; ma.VscP_a = VscP_a;
        ma.xs_w = xs_w; ma.a_s_w = a_s_w;
        ma.src_w = e_w; ma.dst_w = e_w + Ew; ma.src_c = e_c; ma.dst_c = e_c + Ec;
        ma.Ew = Ew; ma.nself_w = nself_w; ma.Ec = Ec; ma.nself_c = nself_c;
        ma.off2 = off2; ma.rank = rank; ma.srcu = srcu;
        ma.PB = (Np + BM - 1) / BM;
        ma.AB = (Na + BM - 1) / BM;
        int SB = (tot_all + 255) / 256;
        mega<<<ma.PB + ma.AB + SB, 256, 0, stream>>>(ma);
    }

    gat_gather<<<(Np + 3) / 4, 256, 0, stream>>>(off2, srcu,
                                                 a_s_w, a_d_w, a_s_c, a_d_c,
                                                 xs_w, xs_c, gat, Np);

    gn_reduce<<<(Np + GN_ROWS - 1) / GN_ROWS, 128, 0, stream>>>(gat, bsum, colsum, colsumsq, Np);

    {
        int FB = (Np + BM - 1) / BM;
        long n4 = (long)Na * DHID / 4;
        final_fill<<<FB + 391, 256, 0, stream>>>(
            gat, bsum, colsum, colsumsq, gnw_p, gnb_p, gnm_p, W2P_p, b2p,
            (float*)d_out, Np, FB,
            row_a, (float4*)((float*)d_out + (size_t)Np * DHID), n4);
    }
}

// Round 9
// 305.400 us; speedup vs baseline: 1.0184x; 1.0184x over previous
//
#include <hip/hip_runtime.h>
#include <cstdint>
#include <cstddef>

#define H 8
#define DHID 128
#define BM 64            // rows per MFMA block
#define LDST 136         // padded LDS row stride (bf16 elems)
#define NEG_SLOPE 0.2f
#define GN_EPS 1e-5f

#define SCAN_T 256
#define SCAN_I 4         // 1024 elements per scan block; requires 2*Np <= 256*1024

typedef __attribute__((ext_vector_type(8))) short short8;
typedef __attribute__((ext_vector_type(4))) float f32x4;

__device__ __forceinline__ void atomAddF(float* p, float v) {
    __hip_atomic_fetch_add(p, v, __ATOMIC_RELAXED, __HIP_MEMORY_SCOPE_AGENT);
}
__device__ __forceinline__ unsigned short f2bf(float f) {
    uint32_t u = __float_as_uint(f);
    uint32_t r = (u + 0x7FFFu + ((u >> 16) & 1u)) >> 16;
    return (unsigned short)r;
}
__device__ __forceinline__ uint32_t pack2bf(float lo, float hi) {
    return (uint32_t)f2bf(lo) | ((uint32_t)f2bf(hi) << 16);
}
__device__ __forceinline__ float bflo(uint32_t v) { return __uint_as_float(v << 16); }
__device__ __forceinline__ float bfhi(uint32_t v) { return __uint_as_float(v & 0xFFFF0000u); }

// ---------------------------------------------------------------------------
// K1: prep (pack weights -> MFMA B-frags, attention fold inline, misc init)
//     ∥ deg_hist; hist records each edge's rank within its dst segment
//     (atomicAdd return) -> rank[], enabling the atomic-free scatter.
// ---------------------------------------------------------------------------
struct PrepHist {
    const float *Wlp, *Wsc, *Wla, *Wsw, *W2p;
    const float *Wdw, *adw, *asc_, *Wdc, *adc_, *asw_;
    unsigned short *WlinP_p, *WsrcP_c, *WlinP_a, *WsrcP_w, *W2P_p, *VscP_p, *VscP_a;
    const float *bw, *bc, *gnb_a, *W2a, *b2a;
    float *bsum, *row_a, *colsum, *colsumsq;
    unsigned short *xs_w_ph, *xs_c_ph;
    float *as_w_ph, *as_c_ph;
    const int *dst_w, *dst_c;
    int *deg, *rank;
    int Ew, nself_w, Ec, nself_c, Np, HB0;
};

__global__ void prep_hist(PrepHist a) {
    int b = blockIdx.x, t = threadIdx.x;
    if (b >= a.HB0) {
        int i = (b - a.HB0) * 256 + t;
        int tw = a.Ew + a.nself_w;
        if (i < tw) {
            int d = (i < a.Ew) ? a.dst_w[i] : (i - a.Ew);
            a.rank[i] = atomicAdd(&a.deg[d], 1);
        } else {
            int j = i - tw;
            if (j < a.Ec + a.nself_c) {
                int d = (j < a.Ec) ? a.dst_c[j] : (j - a.Ec);
                a.rank[i] = atomicAdd(&a.deg[a.Np + d], 1);
            }
        }
        return;
    }
    if (b == 56) {
        if (t < 128) {
            a.bsum[t] = a.bw[t] + a.bc[t];
            float acc = a.b2a[t];
            for (int k = 0; k < DHID; ++k) acc += a.gnb_a[k] * a.W2a[k * DHID + t];
            a.row_a[t] = acc;
            a.colsum[t] = 0.f;
            a.colsumsq[t] = 0.f;
            a.xs_w_ph[t] = 0;
            a.xs_c_ph[t] = 0;
        } else if (t < 136) a.as_w_ph[t - 128] = -1e30f;
        else if (t < 144) a.as_c_ph[t - 136] = -1e30f;
        return;
    }
    int j = b >> 3;
    int idx = (b & 7) * 256 + t;
    int lane = idx & 63, kk = (idx >> 6) & 3, nt = idx >> 8;
    int col = nt * 16 + (lane & 15);
    int k0 = kk * 32 + ((lane >> 4) << 3);
    if (j < 5) {
        const float* W = j == 0 ? a.Wlp : j == 1 ? a.Wsc : j == 2 ? a.Wla : j == 3 ? a.Wsw : a.W2p;
        unsigned short* out = j == 0 ? a.WlinP_p : j == 1 ? a.WsrcP_c : j == 2 ? a.WlinP_a
                              : j == 3 ? a.WsrcP_w : a.W2P_p;
        for (int i = 0; i < 8; ++i) out[idx * 8 + i] = f2bf(W[(k0 + i) * DHID + col]);
    } else if (j == 5) {
        if (idx >= 2 * 256) return;
        const float *W = nullptr, *A = nullptr;
        int h = col & 7;
        if (col < 24) {
            int which = col >> 3;
            W = which == 0 ? a.Wdw : which == 1 ? a.Wsc : a.Wdc;
            A = which == 0 ? a.adw : which == 1 ? a.asc_ : a.adc_;
        }
        for (int i = 0; i < 8; ++i) {
            float v = 0.f;
            if (W)
                for (int c = 0; c < 16; ++c) v += W[(k0 + i) * DHID + h * 16 + c] * A[h * 16 + c];
            a.VscP_p[idx * 8 + i] = f2bf(v);
        }
    } else {
        if (idx >= 256) return;
        int h = col & 7;
        for (int i = 0; i < 8; ++i) {
            float v = 0.f;
            if (col < 8)
                for (int c = 0; c < 16; ++c)
                    v += a.Wsw[(k0 + i) * DHID + h * 16 + c] * a.asw_[h * 16 + c];
            a.VscP_a[idx * 8 + i] = f2bf(v);
        }
    }
}

// ---------------------------------------------------------------------------
// Exclusive scan pass 1 (per-block) with pad-to-4; bsums collects block totals.
// ---------------------------------------------------------------------------
__global__ void scan1(const int* __restrict__ in, int n, int* __restrict__ out,
                      int* __restrict__ bsums) {
    __shared__ int sh[SCAN_T];
    int t = threadIdx.x;
    long base = (long)blockIdx.x * SCAN_T * SCAN_I;
    int v[SCAN_I];
    int s = 0;
#pragma unroll
    for (int j = 0; j < SCAN_I; ++j) {
        long idx = base + (long)t * SCAN_I + j;
        int x = (idx < n) ? in[idx] : 0;
        x = (x + 3) & ~3;               // pad each segment to multiple of 4
        v[j] = x;
        s += x;
    }
    sh[t] = s;
    __syncthreads();
    for (int off = 1; off < SCAN_T; off <<= 1) {
        int x = (t >= off) ? sh[t - off] : 0;
        __syncthreads();
        sh[t] += x;
        __syncthreads();
    }
    int run = sh[t] - s;
#pragma unroll
    for (int j = 0; j < SCAN_I; ++j) {
        long idx = base + (long)t * SCAN_I + j;
        if (idx < n) out[idx] = run;
        run += v[j];
    }
    if (t == SCAN_T - 1) bsums[blockIdx.x] = sh[SCAN_T - 1];
}

// ---------------------------------------------------------------------------
// scan3_prefill: scans bs1 (nb <= 256) in-LDS, then off2 = off_raw + prefix,
// writes sentinel off2[n2], and prefills srcu with phantom ids.
// ---------------------------------------------------------------------------
__global__ void scan3_prefill(const int* __restrict__ off_raw, const int* __restrict__ bs1,
                              int nb, int n2, int* __restrict__ off2,
                              int Np, int Na, int maxTot, int* __restrict__ srcu) {
    __shared__ int pf[SCAN_T];      // inclusive prefix of bs1
    int t = threadIdx.x;
    pf[t] = (t < nb) ? bs1[t] : 0;
    __syncthreads();
    for (int off = 1; off < SCAN_T; off <<= 1) {
        int x = (t >= off) ? pf[t - off] : 0;
        __syncthreads();
        pf[t] += x;
        __syncthreads();
    }
    // exclusive(g) = g ? pf[g-1] : 0
    int i = blockIdx.x * 256 + t;
    if (i < n2) {
        int g = i >> 10;
        off2[i] = off_raw[i] + (g ? pf[g - 1] : 0);
    }
    if (blockIdx.x == 0 && t == 0) off2[n2] = pf[nb - 1];   // total (padded)
    int gm = Np >> 10;
    int mid = off_raw[Np] + (gm ? pf[gm - 1] : 0);
    long stride = (long)gridDim.x * 256;
    for (long k = i; k < maxTot; k += stride) srcu[k] = (k < (long)mid) ? Na : Np;
}

// ---------------------------------------------------------------------------
// MFMA projection body (paper NSC=2 / author NSC=1)
// ---------------------------------------------------------------------------
template <int NSC>
__device__ void proj_body(unsigned short* xt, int bid,
                          const float* __restrict__ x, int nrows,
                          const unsigned short* __restrict__ WlinP, const float* __restrict__ blin,
                          const unsigned short* __restrict__ WsrcP,
                          const unsigned short* __restrict__ VscP,
                          unsigned short* __restrict__ xs,
                          float* __restrict__ a0, float* __restrict__ a1, float* __restrict__ a2) {
    int t = threadIdx.x;
    int lane = t & 63, w = t >> 6;
    long row0 = (long)bid * BM;
    for (int it = 0; it < 16; ++it) {
        int idx2 = t + it * 256;
        int r = idx2 >> 6, cp = idx2 & 63;
        long gr = row0 + r;
        float v0 = 0.f, v1 = 0.f;
        if (gr < nrows) { v0 = x[gr * DHID + 2 * cp]; v1 = x[gr * DHID + 2 * cp + 1]; }
        *reinterpret_cast<uint32_t*>(&xt[r * LDST + 2 * cp]) = pack2bf(v0, v1);
    }
    __syncthreads();
    int arow = w * 16 + (lane & 15);
    int koff = (lane >> 4) << 3;
    short8 af[4];
#pragma unroll
    for (int kk = 0; kk < 4; ++kk)
        af[kk] = *reinterpret_cast<const short8*>(&xt[arow * LDST + kk * 32 + koff]);
    const short8* Bl = reinterpret_cast<const short8*>(WlinP);
    f32x4 acc[8];
#pragma unroll
    for (int nt = 0; nt < 8; ++nt) {
        f32x4 a = {0.f, 0.f, 0.f, 0.f};
#pragma unroll
        for (int kk = 0; kk < 4; ++kk)
            a = __builtin_amdgcn_mfma_f32_16x16x32_bf16(af[kk], Bl[(nt * 4 + kk) * 64 + lane], a, 0, 0, 0);
        acc[nt] = a;
    }
    __syncthreads();
    int orow = w * 16 + ((lane >> 4) << 2);
    int ccol = lane & 15;
#pragma unroll
    for (int nt = 0; nt < 8; ++nt) {
        float b = blin[nt * 16 + ccol];
#pragma unroll
        for (int r = 0; r < 4; ++r) {
            float e = fmaxf(acc[nt][r] + b, 0.f);
            xt[(orow + r) * LDST + nt * 16 + ccol] = f2bf(e);
        }
    }
    __syncthreads();
#pragma unroll
    for (int kk = 0; kk < 4; ++kk)
        af[kk] = *reinterpret_cast<const short8*>(&xt[arow * LDST + kk * 32 + koff]);
    const short8* Bs = reinterpret_cast<const short8*>(WsrcP);
#pragma unroll
    for (int nt = 0; nt < 8; ++nt) {
        f32x4 a = {0.f, 0.f, 0.f, 0.f};
#pragma unroll
        for (int kk = 0; kk < 4; ++kk)
            a = __builtin_amdgcn_mfma_f32_16x16x32_bf16(af[kk], Bs[(nt * 4 + kk) * 64 + lane], a, 0, 0, 0);
        acc[nt] = a;
    }
    const short8* Bv = reinterpret_cast<const short8*>(VscP);
    f32x4 sacc0 = {0.f, 0.f, 0.f, 0.f}, sacc1 = {0.f, 0.f, 0.f, 0.f};
#pragma unroll
    for (int kk = 0; kk < 4; ++kk)
        sacc0 = __builtin_amdgcn_mfma_f32_16x16x32_bf16(af[kk], Bv[kk * 64 + lane], sacc0, 0, 0, 0);
    if (NSC > 1) {
#pragma unroll
        for (int kk = 0; kk < 4; ++kk)
            sacc1 = __builtin_amdgcn_mfma_f32_16x16x32_bf16(af[kk], Bv[(4 + kk) * 64 + lane], sacc1, 0, 0, 0);
    }
#pragma unroll
    for (int nt = 0; nt < 8; ++nt) {
#pragma unroll
        for (int r = 0; r < 4; ++r) {
            long gr = row0 + orow + r;
            if (gr < nrows) xs[gr * DHID + nt * 16 + ccol] = f2bf(acc[nt][r]);
        }
    }
#pragma unroll
    for (int st = 0; st < NSC; ++st) {
        int scol = st * 16 + ccol;
        int h = scol & 7, which = scol >> 3;
        float* ap = which == 0 ? a0 : which == 1 ? a1 : which == 2 ? a2 : nullptr;
        if (ap) {
            f32x4 s = st == 0 ? sacc0 : sacc1;
#pragma unroll
            for (int r = 0; r < 4; ++r) {
                long gr = row0 + orow + r;
                if (gr < nrows) ap[gr * H + h] = s[r];
            }
        }
    }
}

// ---------------------------------------------------------------------------
// K4 MEGA: proj_paper, proj_author, then atomic-free csr_scatter
// (sequential role layout — round-7 ordering; slot-sharing interleave hurt).
// ---------------------------------------------------------------------------
struct MegaArgs {
    const float* x_p; int Np;
    const unsigned short* WlinP_p; const float* blp;
    const unsigned short* WsrcP_c; const unsigned short* VscP_p;
    unsigned short* xs_c; float *a_d_w, *a_s_c, *a_d_c;
    const float* x_a; int Na;
    const unsigned short* WlinP_a; const float* bla;
    const unsigned short* WsrcP_w; const unsigned short* VscP_a;
    unsigned short* xs_w; float* a_s_w;
    const int *src_w, *dst_w, *src_c, *dst_c;
    int Ew, nself_w, Ec, nself_c;
    const int *off2, *rank;
    int* srcu;
    int PB, AB;
};

__global__ __launch_bounds__(256) void mega(MegaArgs a) {
    __shared__ unsigned short xt[BM * LDST];
    int b = blockIdx.x;
    if (b < a.PB) {
        proj_body<2>(xt, b, a.x_p, a.Np, a.WlinP_p, a.blp, a.WsrcP_c, a.VscP_p,
                     a.xs_c, a.a_d_w, a.a_s_c, a.a_d_c);
        return;
    }
    if (b < a.PB + a.AB) {
        proj_body<1>(xt, b - a.PB, a.x_a, a.Na, a.WlinP_a, a.bla, a.WsrcP_w, a.VscP_a,
                     a.xs_w, a.a_s_w, nullptr, nullptr);
        return;
    }
    int i = (b - a.PB - a.AB) * 256 + threadIdx.x;
    int tw = a.Ew + a.nself_w;
    int s, di;
    if (i < tw) {
        if (i < a.Ew) { s = a.src_w[i]; di = a.dst_w[i]; } else { s = di = i - a.Ew; }
    } else {
        int j = i - tw;
        if (j >= a.Ec + a.nself_c) return;
        if (j < a.Ec) { s = a.src_c[j]; di = a.Np + a.dst_c[j]; }
        else { s = j - a.Ec; di = a.Np + (j - a.Ec); }
    }
    a.srcu[a.off2[di] + a.rank[i]] = s;
}

// ---------------------------------------------------------------------------
// Gather: writes gat as packed bf16 pairs (uint32 per 2 cols).
// ---------------------------------------------------------------------------
__global__ __launch_bounds__(256) void gat_gather(
    const int* __restrict__ off, const int* __restrict__ srcu,
    const float* __restrict__ a_s_w, const float* __restrict__ a_d_w,
    const float* __restrict__ a_s_c, const float* __restrict__ a_d_c,
    const unsigned short* __restrict__ xs_w, const unsigned short* __restrict__ xs_c,
    uint32_t* __restrict__ gatb, int Np) {
    int l = threadIdx.x & 63;
    int d = blockIdx.x * 4 + (threadIdx.x >> 6);
    if (d >= Np) return;
    int h = l >> 3;
    int iw = off[d], w1 = off[d + 1];
    int ic = off[Np + d], c1 = off[Np + d + 1];
    float adw = a_d_w[(long)d * H + h];
    float adc = a_d_c[(long)d * H + h];
    float denw = 0.f, n0w = 0.f, n1w = 0.f;
    float denc = 0.f, n0c = 0.f, n1c = 0.f;
    while (iw < w1 || ic < c1) {
        bool hw = iw < w1, hc = ic < c1;
        int4 sw, sc;
        if (hw) sw = *reinterpret_cast<const int4*>(srcu + iw);
        if (hc) sc = *reinterpret_cast<const int4*>(srcu + ic);
        float ew[4], ec[4];
        uint32_t vw[4], vc[4];
        if (hw) {
            ew[0] = a_s_w[(long)sw.x * H + h];
            ew[1] = a_s_w[(long)sw.y * H + h];
            ew[2] = a_s_w[(long)sw.z * H + h];
            ew[3] = a_s_w[(long)sw.w * H + h];
            vw[0] = *reinterpret_cast<const uint32_t*>(xs_w + (long)sw.x * DHID + 2 * l);
            vw[1] = *reinterpret_cast<const uint32_t*>(xs_w + (long)sw.y * DHID + 2 * l);
            vw[2] = *reinterpret_cast<const uint32_t*>(xs_w + (long)sw.z * DHID + 2 * l);
            vw[3] = *reinterpret_cast<const uint32_t*>(xs_w + (long)sw.w * DHID + 2 * l);
        }
        if (hc) {
            ec[0] = a_s_c[(long)sc.x * H + h];
            ec[1] = a_s_c[(long)sc.y * H + h];
            ec[2] = a_s_c[(long)sc.z * H + h];
            ec[3] = a_s_c[(long)sc.w * H + h];
            vc[0] = *reinterpret_cast<const uint32_t*>(xs_c + (long)sc.x * DHID + 2 * l);
            vc[1] = *reinterpret_cast<const uint32_t*>(xs_c + (long)sc.y * DHID + 2 * l);
            vc[2] = *reinterpret_cast<const uint32_t*>(xs_c + (long)sc.z * DHID + 2 * l);
            vc[3] = *reinterpret_cast<const uint32_t*>(xs_c + (long)sc.w * DHID + 2 * l);
        }
        if (hw) {
#pragma unroll
            for (int j = 0; j < 4; ++j) {
                float e = ew[j] + adw;
                e = e > 0.f ? e : NEG_SLOPE * e;
                float p = __expf(e);
                denw += p;
                n0w += p * bflo(vw[j]);
                n1w += p * bfhi(vw[j]);
            }
            iw += 4;
        }
        if (hc) {
#pragma unroll
            for (int j = 0; j < 4; ++j) {
                float e = ec[j] + adc;
                e = e > 0.f ? e : NEG_SLOPE * e;
                float p = __expf(e);
                denc += p;
                n0c += p * bflo(vc[j]);
                n1c += p * bfhi(vc[j]);
            }
            ic += 4;
        }
    }
    float rw = 1.f / (denw + 1e-16f);
    float rc = 1.f / (denc + 1e-16f);
    gatb[(long)d * 64 + l] = pack2bf(n0w * rw + n0c * rc, n1w * rw + n1c * rc);
}

// ---------------------------------------------------------------------------
// GraphNorm reduction over bf16-packed gat. 256 thr: pair p=t&63, row off t>>6.
// ---------------------------------------------------------------------------
#define GN_ROWS 512
__global__ void gn_reduce(const uint32_t* __restrict__ gatb, const float* __restrict__ bsum,
                          float* __restrict__ colsum, float* __restrict__ colsumsq, int Np) {
    int t = threadIdx.x;
    int p = t & 63, ro = t >> 6;
    long r0 = (long)blockIdx.x * GN_ROWS + ro;
    long r1 = min((long)(blockIdx.x + 1) * GN_ROWS, (long)Np);
    float b0 = bsum[2 * p], b1 = bsum[2 * p + 1];
    float s1a = 0.f, s2a = 0.f, s1b = 0.f, s2b = 0.f;
    for (long r = r0; r < r1; r += 4) {
        uint32_t u = gatb[r * 64 + p];
        float x0 = bflo(u) + b0, x1 = bfhi(u) + b1;
        s1a += x0; s2a += x0 * x0;
        s1b += x1; s2b += x1 * x1;
    }
    atomAddF(colsum + 2 * p, s1a);
    atomAddF(colsumsq + 2 * p, s2a);
    atomAddF(colsum + 2 * p + 1, s1b);
    atomAddF(colsumsq + 2 * p + 1, s2b);
}

// ---------------------------------------------------------------------------
// K7: final_mfma (paper gnorm + @W2 + b2, bf16 gat input) ∥ author fill
// ---------------------------------------------------------------------------
__global__ __launch_bounds__(256) void final_fill(
    const uint32_t* __restrict__ gatb, const float* __restrict__ bsum,
    const float* __restrict__ colsum, const float* __restrict__ colsumsq,
    const float* __restrict__ gnw, const float* __restrict__ gnb,
    const float* __restrict__ gnm,
    const unsigned short* __restrict__ W2P, const float* __restrict__ b2,
    float* __restrict__ out, int Np, int FB,
    const float* __restrict__ row_a, float4* __restrict__ outa, long n4) {
    __shared__ unsigned short xt[BM * LDST];
    __shared__ float cscale[DHID], cshift[DHID];
    int b = blockIdx.x;
    int t = threadIdx.x;
    if (b >= FB) {
        long i = (long)(b - FB) * 256 + t;
        long stride = (long)(gridDim.x - FB) * 256;
        const float4* r4 = reinterpret_cast<const float4*>(row_a);
        for (; i < n4; i += stride) outa[i] = r4[i & 31];
        return;
    }
    int lane = t & 63, w = t >> 6;
    long row0 = (long)b * BM;
    if (t < DHID) {
        float invN = 1.f / (float)Np;
        float mu = colsum[t] * invN;
        float ms = gnm[t];
        float var = colsumsq[t] * invN - mu * mu * ms * (2.f - ms);
        float sc = gnw[t] * rsqrtf(var + GN_EPS);
        cscale[t] = sc;
        cshift[t] = (bsum[t] - ms * mu) * sc + gnb[t];
    }
    __syncthreads();
    for (int it = 0; it < 16; ++it) {
        int idx2 = t + it * 256;
        int r = idx2 >> 6, cp = idx2 & 63;
        long gr = row0 + r;
        float v0 = 0.f, v1 = 0.f;
        if (gr < Np) {
            uint32_t u = gatb[gr * 64 + cp];
            v0 = bflo(u) * cscale[2 * cp] + cshift[2 * cp];
            v1 = bfhi(u) * cscale[2 * cp + 1] + cshift[2 * cp + 1];
        }
        *reinterpret_cast<uint32_t*>(&xt[r * LDST + 2 * cp]) = pack2bf(v0, v1);
    }
    __syncthreads();
    int arow = w * 16 + (lane & 15);
    int koff = (lane >> 4) << 3;
    short8 af[4];
#pragma unroll
    for (int kk = 0; kk < 4; ++kk)
        af[kk] = *reinterpret_cast<const short8*>(&xt[arow * LDST + kk * 32 + koff]);
    const short8* Bw = reinterpret_cast<const short8*>(W2P);
    int orow = w * 16 + ((lane >> 4) << 2);
    int ccol = lane & 15;
#pragma unroll
    for (int nt = 0; nt < 8; ++nt) {
        f32x4 a = {0.f, 0.f, 0.f, 0.f};
#pragma unroll
        for (int kk = 0; kk < 4; ++kk)
            a = __builtin_amdgcn_mfma_f32_16x16x32_bf16(af[kk], Bw[(nt * 4 + kk) * 64 + lane], a, 0, 0, 0);
        float bb = b2[nt * 16 + ccol];
#pragma unroll
        for (int r = 0; r < 4; ++r) {
            long gr = row0 + orow + r;
            if (gr < Np) out[gr * DHID + nt * 16 + ccol] = a[r] + bb;
        }
    }
}

// ---------------------------------------------------------------------------
extern "C" void kernel_launch(void* const* d_in, const int* in_sizes, int n_in,
                              void* d_out, int out_size, void* d_ws, size_t ws_size,
                              hipStream_t stream) {
    const float* x_p   = (const float*)d_in[0];
    const float* x_a   = (const float*)d_in[1];
    const int*   e_w   = (const int*)d_in[2];
    const int*   e_c   = (const int*)d_in[3];
    const float* Wlp   = (const float*)d_in[4];
    const float* blp   = (const float*)d_in[5];
    const float* Wla   = (const float*)d_in[6];
    const float* bla   = (const float*)d_in[7];
    const float* Wsw   = (const float*)d_in[8];
    const float* Wdw   = (const float*)d_in[9];
    const float* asw   = (const float*)d_in[10];
    const float* adw   = (const float*)d_in[11];
    const float* bw    = (const float*)d_in[12];
    const float* Wsc   = (const float*)d_in[13];
    const float* Wdc   = (const float*)d_in[14];
    const float* asc   = (const float*)d_in[15];
    const float* adc   = (const float*)d_in[16];
    const float* bc    = (const float*)d_in[17];
    const float* gnw_p = (const float*)d_in[18];
    const float* gnb_p = (const float*)d_in[19];
    const float* gnm_p = (const float*)d_in[20];
    const float* gnb_a = (const float*)d_in[22];
    const float* W2p   = (const float*)d_in[24];
    const float* b2p   = (const float*)d_in[25];
    const float* W2a   = (const float*)d_in[26];
    const float* b2a   = (const float*)d_in[27];

    int Np = in_sizes[0] / DHID;
    int Na = in_sizes[1] / DHID;
    int Ew = in_sizes[2] / 2;
    int Ec = in_sizes[3] / 2;
    int nself_w = Na < Np ? Na : Np;
    int nself_c = Np;
    int tot_all = (Ew + nself_w) + (Ec + nself_c);
    int maxTot = tot_all + 6 * Np + 8;

    float* ws = (float*)d_ws;
    uint32_t* gatb = (uint32_t*)ws;                    // Np*64 (bf16 pairs)
    float* a_d_w = (float*)(gatb + (size_t)Np * 64);   // Np*8
    float* a_d_c = a_d_w + (size_t)Np * H;             // Np*8
    float* a_s_w = a_d_c + (size_t)Np * H;             // (Na+1)*8
    float* a_s_c = a_s_w + (size_t)(Na + 1) * H;       // (Np+1)*8
    float* bsum  = a_s_c + (size_t)(Np + 1) * H;       // 128
    float* row_a = bsum + DHID;                        // 128
    float* colsum   = row_a + DHID;                    // 128
    float* colsumsq = colsum + DHID;                   // 128
    int*   deg   = (int*)(colsumsq + DHID);            // 2*Np (memset)
    int* off_raw = deg + 2 * Np;                       // 2*Np
    int* off2    = off_raw + 2 * Np;                   // 2*Np + 1
    int* bs1     = off2 + 2 * Np + 1;                  // 512
    uintptr_t up = (uintptr_t)(bs1 + 512);
    up = (up + 15) & ~(uintptr_t)15;
    int* srcu = (int*)up;                              // maxTot
    int* rank = srcu + maxTot;                         // tot_all
    unsigned short* xs_w = (unsigned short*)(rank + tot_all);  // (Na+1)*128
    unsigned short* xs_c = xs_w + (size_t)(Na + 1) * DHID;     // (Np+1)*128
    up = (uintptr_t)(xs_c + (size_t)(Np + 1) * DHID);
    up = (up + 15) & ~(uintptr_t)15;
    unsigned short* WlinP_p = (unsigned short*)up;
    unsigned short* WsrcP_c = WlinP_p + 16384;
    unsigned short* WlinP_a = WsrcP_c + 16384;
    unsigned short* WsrcP_w = WlinP_a + 16384;
    unsigned short* W2P_p   = WsrcP_w + 16384;
    unsigned short* VscP_p  = W2P_p + 16384;
    unsigned short* VscP_a  = VscP_p + 4096;

    hipMemsetAsync(deg, 0, 2 * (size_t)Np * sizeof(int), stream);

    int HB = (tot_all + 255) / 256;
    {
        PrepHist pa;
        pa.Wlp = Wlp; pa.Wsc = Wsc; pa.Wla = Wla; pa.Wsw = Wsw; pa.W2p = W2p;
        pa.Wdw = Wdw; pa.adw = adw; pa.asc_ = asc; pa.Wdc = Wdc; pa.adc_ = adc; pa.asw_ = asw;
        pa.WlinP_p = WlinP_p; pa.WsrcP_c = WsrcP_c; pa.WlinP_a = WlinP_a;
        pa.WsrcP_w = WsrcP_w; pa.W2P_p = W2P_p; pa.VscP_p = VscP_p; pa.VscP_a = VscP_a;
        pa.bw = bw; pa.bc = bc; pa.gnb_a = gnb_a; pa.W2a = W2a; pa.b2a = b2a;
        pa.bsum = bsum; pa.row_a = row_a; pa.colsum = colsum; pa.colsumsq = colsumsq;
        pa.xs_w_ph = xs_w + (size_t)Na * DHID;
        pa.xs_c_ph = xs_c + (size_t)Np * DHID;
        pa.as_w_ph = a_s_w + (size_t)Na * H;
        pa.as_c_ph = a_s_c + (size_t)Np * H;
        pa.dst_w = e_w + Ew; pa.dst_c = e_c + Ec;
        pa.deg = deg; pa.rank = rank;
        pa.Ew = Ew; pa.nself_w = nself_w; pa.Ec = Ec; pa.nself_c = nself_c;
        pa.Np = Np; pa.HB0 = 57;
        prep_hist<<<57 + HB, 256, 0, stream>>>(pa);
    }

    int n2 = 2 * Np;
    int nb = (n2 + SCAN_T * SCAN_I - 1) / (SCAN_T * SCAN_I);   // must be <= 256
    scan1<<<nb, SCAN_T, 0, stream>>>(deg, n2, off_raw, bs1);

    scan3_prefill<<<(maxTot + 255) / 256, 256, 0, stream>>>(
        off_raw, bs1, nb, n2, off2, Np, Na, maxTot, srcu);

    {
        MegaArgs ma;
        ma.x_p = x_p; ma.Np = Np; ma.WlinP_p = WlinP_p; ma.blp = blp;
        ma.WsrcP_c = WsrcP_c; ma.VscP_p = VscP_p;
        ma.xs_c = xs_c; ma.a_d_w = a_d_w; ma.a_s_c = a_s_c; ma.a_d_c = a_d_c;
        ma.x_a = x_a; ma.Na = Na; ma.WlinP_a = WlinP_a; ma.bla = bla;
        ma.WsrcP_w = WsrcP_w; ma.VscP_a = VscP_a;
        ma.xs_w = xs_w; ma.a_s_w = a_s_w;
        ma.src_w = e_w; ma.dst_w = e_w + Ew; ma.src_c = e_c; ma.dst_c = e_c + Ec;
        ma.Ew = Ew; ma.nself_w = nself_w; ma.Ec = Ec; ma.nself_c = nself_c;
        ma.off2 = off2; ma.rank = rank; ma.srcu = srcu;
        ma.PB = (Np + BM - 1) / BM;
        ma.AB = (Na + BM - 1) / BM;
        int SB = (tot_all + 255) / 256;
        mega<<<ma.PB + ma.AB + SB, 256, 0, stream>>>(ma);
    }

    gat_gather<<<(Np + 3) / 4, 256, 0, stream>>>(off2, srcu,
                                                 a_s_w, a_d_w, a_s_c, a_d_c,
                                                 xs_w, xs_c, gatb, Np);

    gn_reduce<<<(Np + GN_ROWS - 1) / GN_ROWS, 256, 0, stream>>>(gatb, bsum, colsum, colsumsq, Np);

    {
        int FB = (Np + BM - 1) / BM;
        long n4 = (long)Na * DHID / 4;
        final_fill<<<FB + 391, 256, 0, stream>>>(
            gatb, bsum, colsum, colsumsq, gnw_p, gnb_p, gnm_p, W2P_p, b2p,
            (float*)d_out, Np, FB,
            row_a, (float4*)((float*)d_out + (size_t)Np * DHID), n4);
    }
}

// Round 10
// 301.543 us; speedup vs baseline: 1.0315x; 1.0128x over previous
//
#include <hip/hip_runtime.h>
#include <cstdint>
#include <cstddef>

#define H 8
#define DHID 128
#define BM 64            // rows per MFMA block
#define LDST 136         // padded LDS row stride (bf16 elems)
#define NEG_SLOPE 0.2f
#define GN_EPS 1e-5f

#define SCAN_T 256
#define SCAN_I 4         // 1024 elements per scan block; requires 2*Np <= 256*1024

typedef __attribute__((ext_vector_type(8))) short short8;
typedef __attribute__((ext_vector_type(4))) float f32x4;

__device__ __forceinline__ void atomAddF(float* p, float v) {
    __hip_atomic_fetch_add(p, v, __ATOMIC_RELAXED, __HIP_MEMORY_SCOPE_AGENT);
}
__device__ __forceinline__ unsigned short f2bf(float f) {
    uint32_t u = __float_as_uint(f);
    uint32_t r = (u + 0x7FFFu + ((u >> 16) & 1u)) >> 16;
    return (unsigned short)r;
}
__device__ __forceinline__ uint32_t pack2bf(float lo, float hi) {
    return (uint32_t)f2bf(lo) | ((uint32_t)f2bf(hi) << 16);
}
__device__ __forceinline__ float bflo(uint32_t v) { return __uint_as_float(v << 16); }
__device__ __forceinline__ float bfhi(uint32_t v) { return __uint_as_float(v & 0xFFFF0000u); }

// load 8 consecutive f32 from global, convert to bf16 MFMA fragment
__device__ __forceinline__ short8 frag_from_f32(const float* __restrict__ p) {
    float4 a = *reinterpret_cast<const float4*>(p);
    float4 b = *reinterpret_cast<const float4*>(p + 4);
    uint32_t arr[4] = {pack2bf(a.x, a.y), pack2bf(a.z, a.w),
                       pack2bf(b.x, b.y), pack2bf(b.z, b.w)};
    return *reinterpret_cast<short8*>(arr);
}

// ---------------------------------------------------------------------------
// K1: prep (pack weights -> MFMA B-frags, attention fold inline, misc init)
//     ∥ deg_hist over REAL edges only (self-loops handled analytically in the
//     gather); hist records each edge's rank within its dst segment.
// ---------------------------------------------------------------------------
struct PrepHist {
    const float *Wlp, *Wsc, *Wla, *Wsw, *W2p;
    const float *Wdw, *adw, *asc_, *Wdc, *adc_, *asw_;
    unsigned short *WlinP_p, *WsrcP_c, *WlinP_a, *WsrcP_w, *W2P_p, *VscP_p, *VscP_a;
    const float *bw, *bc, *gnb_a, *W2a, *b2a;
    float *bsum, *row_a, *colsum, *colsumsq;
    unsigned short *xs_w_ph, *xs_c_ph;
    float *as_w_ph, *as_c_ph;
    const int *dst_w, *dst_c;
    int *deg, *rank;
    int Ew, Ec, Np, HB0;
};

__global__ void prep_hist(PrepHist a) {
    int b = blockIdx.x, t = threadIdx.x;
    if (b >= a.HB0) {
        int i = (b - a.HB0) * 256 + t;
        if (i < a.Ew) {
            int d = a.dst_w[i];
            a.rank[i] = atomicAdd(&a.deg[d], 1);
        } else if (i < a.Ew + a.Ec) {
            int d = a.dst_c[i - a.Ew];
            a.rank[i] = atomicAdd(&a.deg[a.Np + d], 1);
        }
        return;
    }
    if (b == 56) {
        if (t < 128) {
            a.bsum[t] = a.bw[t] + a.bc[t];
            float acc = a.b2a[t];
            for (int k = 0; k < DHID; ++k) acc += a.gnb_a[k] * a.W2a[k * DHID + t];
            a.row_a[t] = acc;
            a.colsum[t] = 0.f;
            a.colsumsq[t] = 0.f;
            a.xs_w_ph[t] = 0;
            a.xs_c_ph[t] = 0;
        } else if (t < 136) a.as_w_ph[t - 128] = -1e30f;
        else if (t < 144) a.as_c_ph[t - 136] = -1e30f;
        return;
    }
    int j = b >> 3;
    int idx = (b & 7) * 256 + t;
    int lane = idx & 63, kk = (idx >> 6) & 3, nt = idx >> 8;
    int col = nt * 16 + (lane & 15);
    int k0 = kk * 32 + ((lane >> 4) << 3);
    if (j < 5) {
        const float* W = j == 0 ? a.Wlp : j == 1 ? a.Wsc : j == 2 ? a.Wla : j == 3 ? a.Wsw : a.W2p;
        unsigned short* out = j == 0 ? a.WlinP_p : j == 1 ? a.WsrcP_c : j == 2 ? a.WlinP_a
                              : j == 3 ? a.WsrcP_w : a.W2P_p;
        for (int i = 0; i < 8; ++i) out[idx * 8 + i] = f2bf(W[(k0 + i) * DHID + col]);
    } else if (j == 5) {
        if (idx >= 2 * 256) return;
        const float *W = nullptr, *A = nullptr;
        int h = col & 7;
        if (col < 24) {
            int which = col >> 3;
            W = which == 0 ? a.Wdw : which == 1 ? a.Wsc : a.Wdc;
            A = which == 0 ? a.adw : which == 1 ? a.asc_ : a.adc_;
        }
        for (int i = 0; i < 8; ++i) {
            float v = 0.f;
            if (W)
                for (int c = 0; c < 16; ++c) v += W[(k0 + i) * DHID + h * 16 + c] * A[h * 16 + c];
            a.VscP_p[idx * 8 + i] = f2bf(v);
        }
    } else {
        if (idx >= 256) return;
        int h = col & 7;
        for (int i = 0; i < 8; ++i) {
            float v = 0.f;
            if (col < 8)
                for (int c = 0; c < 16; ++c)
                    v += a.Wsw[(k0 + i) * DHID + h * 16 + c] * a.asw_[h * 16 + c];
            a.VscP_a[idx * 8 + i] = f2bf(v);
        }
    }
}

// ---------------------------------------------------------------------------
// Exclusive scan pass 1 (per-block) with pad-to-4; bsums collects block totals.
// ---------------------------------------------------------------------------
__global__ void scan1(const int* __restrict__ in, int n, int* __restrict__ out,
                      int* __restrict__ bsums) {
    __shared__ int sh[SCAN_T];
    int t = threadIdx.x;
    long base = (long)blockIdx.x * SCAN_T * SCAN_I;
    int v[SCAN_I];
    int s = 0;
#pragma unroll
    for (int j = 0; j < SCAN_I; ++j) {
        long idx = base + (long)t * SCAN_I + j;
        int x = (idx < n) ? in[idx] : 0;
        x = (x + 3) & ~3;               // pad each segment to multiple of 4
        v[j] = x;
        s += x;
    }
    sh[t] = s;
    __syncthreads();
    for (int off = 1; off < SCAN_T; off <<= 1) {
        int x = (t >= off) ? sh[t - off] : 0;
        __syncthreads();
        sh[t] += x;
        __syncthreads();
    }
    int run = sh[t] - s;
#pragma unroll
    for (int j = 0; j < SCAN_I; ++j) {
        long idx = base + (long)t * SCAN_I + j;
        if (idx < n) out[idx] = run;
        run += v[j];
    }
    if (t == SCAN_T - 1) bsums[blockIdx.x] = sh[SCAN_T - 1];
}

// ---------------------------------------------------------------------------
// scan3_prefill: scans bs1 (nb <= 256) in-LDS, then off2 = off_raw + prefix,
// writes sentinel off2[n2], and prefills srcu with phantom ids.
// ---------------------------------------------------------------------------
__global__ void scan3_prefill(const int* __restrict__ off_raw, const int* __restrict__ bs1,
                              int nb, int n2, int* __restrict__ off2,
                              int Np, int Na, int maxTot, int* __restrict__ srcu) {
    __shared__ int pf[SCAN_T];      // inclusive prefix of bs1
    int t = threadIdx.x;
    pf[t] = (t < nb) ? bs1[t] : 0;
    __syncthreads();
    for (int off = 1; off < SCAN_T; off <<= 1) {
        int x = (t >= off) ? pf[t - off] : 0;
        __syncthreads();
        pf[t] += x;
        __syncthreads();
    }
    int i = blockIdx.x * 256 + t;
    if (i < n2) {
        int g = i >> 10;
        off2[i] = off_raw[i] + (g ? pf[g - 1] : 0);
    }
    if (blockIdx.x == 0 && t == 0) off2[n2] = pf[nb - 1];
    int gm = Np >> 10;
    int mid = off_raw[Np] + (gm ? pf[gm - 1] : 0);
    long stride = (long)gridDim.x * 256;
    for (long k = i; k < maxTot; k += stride) srcu[k] = (k < (long)mid) ? Na : Np;
}

// ---------------------------------------------------------------------------
// MFMA projection body (paper NSC=2 / author NSC=1).
// GEMM1 A-fragments loaded DIRECTLY from global f32 (no LDS staging);
// LDS used only for the emb layout roundtrip (one barrier).
// ---------------------------------------------------------------------------
template <int NSC>
__device__ void proj_body(unsigned short* xt, int bid,
                          const float* __restrict__ x, int nrows,
                          const unsigned short* __restrict__ WlinP, const float* __restrict__ blin,
                          const unsigned short* __restrict__ WsrcP,
                          const unsigned short* __restrict__ VscP,
                          unsigned short* __restrict__ xs,
                          float* __restrict__ a0, float* __restrict__ a1, float* __restrict__ a2) {
    int t = threadIdx.x;
    int lane = t & 63, w = t >> 6;
    long row0 = (long)bid * BM;
    int arow = w * 16 + (lane & 15);
    int koff = (lane >> 4) << 3;
    long gra = row0 + arow;
    short8 af[4];
    if (gra < nrows) {
#pragma unroll
        for (int kk = 0; kk < 4; ++kk)
            af[kk] = frag_from_f32(x + gra * DHID + kk * 32 + koff);
    } else {
#pragma unroll
        for (int kk = 0; kk < 4; ++kk) {
#pragma unroll
            for (int i = 0; i < 8; ++i) af[kk][i] = 0;
        }
    }
    // ---- GEMM1: emb = x @ Wlin ----
    const short8* Bl = reinterpret_cast<const short8*>(WlinP);
    f32x4 acc[8];
#pragma unroll
    for (int nt = 0; nt < 8; ++nt) {
        f32x4 a = {0.f, 0.f, 0.f, 0.f};
#pragma unroll
        for (int kk = 0; kk < 4; ++kk)
            a = __builtin_amdgcn_mfma_f32_16x16x32_bf16(af[kk], Bl[(nt * 4 + kk) * 64 + lane], a, 0, 0, 0);
        acc[nt] = a;
    }
    // ---- bias + relu -> emb into LDS (C-layout write) ----
    int orow = w * 16 + ((lane >> 4) << 2);
    int ccol = lane & 15;
#pragma unroll
    for (int nt = 0; nt < 8; ++nt) {
        float b = blin[nt * 16 + ccol];
#pragma unroll
        for (int r = 0; r < 4; ++r) {
            float e = fmaxf(acc[nt][r] + b, 0.f);
            xt[(orow + r) * LDST + nt * 16 + ccol] = f2bf(e);
        }
    }
    __syncthreads();
#pragma unroll
    for (int kk = 0; kk < 4; ++kk)
        af[kk] = *reinterpret_cast<const short8*>(&xt[arow * LDST + kk * 32 + koff]);
    // ---- GEMM2: xs = emb @ Wsrc ----
    const short8* Bs = reinterpret_cast<const short8*>(WsrcP);
#pragma unroll
    for (int nt = 0; nt < 8; ++nt) {
        f32x4 a = {0.f, 0.f, 0.f, 0.f};
#pragma unroll
        for (int kk = 0; kk < 4; ++kk)
            a = __builtin_amdgcn_mfma_f32_16x16x32_bf16(af[kk], Bs[(nt * 4 + kk) * 64 + lane], a, 0, 0, 0);
        acc[nt] = a;
    }
    // ---- scores: emb @ Vsc ----
    const short8* Bv = reinterpret_cast<const short8*>(VscP);
    f32x4 sacc0 = {0.f, 0.f, 0.f, 0.f}, sacc1 = {0.f, 0.f, 0.f, 0.f};
#pragma unroll
    for (int kk = 0; kk < 4; ++kk)
        sacc0 = __builtin_amdgcn_mfma_f32_16x16x32_bf16(af[kk], Bv[kk * 64 + lane], sacc0, 0, 0, 0);
    if (NSC > 1) {
#pragma unroll
        for (int kk = 0; kk < 4; ++kk)
            sacc1 = __builtin_amdgcn_mfma_f32_16x16x32_bf16(af[kk], Bv[(4 + kk) * 64 + lane], sacc1, 0, 0, 0);
    }
#pragma unroll
    for (int nt = 0; nt < 8; ++nt) {
#pragma unroll
        for (int r = 0; r < 4; ++r) {
            long gr = row0 + orow + r;
            if (gr < nrows) xs[gr * DHID + nt * 16 + ccol] = f2bf(acc[nt][r]);
        }
    }
#pragma unroll
    for (int st = 0; st < NSC; ++st) {
        int scol = st * 16 + ccol;
        int h = scol & 7, which = scol >> 3;
        float* ap = which == 0 ? a0 : which == 1 ? a1 : which == 2 ? a2 : nullptr;
        if (ap) {
            f32x4 s = st == 0 ? sacc0 : sacc1;
#pragma unroll
            for (int r = 0; r < 4; ++r) {
                long gr = row0 + orow + r;
                if (gr < nrows) ap[gr * H + h] = s[r];
            }
        }
    }
}

// ---------------------------------------------------------------------------
// K4 MEGA: proj_paper, proj_author, then atomic-free csr_scatter (real edges).
// ---------------------------------------------------------------------------
struct MegaArgs {
    const float* x_p; int Np;
    const unsigned short* WlinP_p; const float* blp;
    const unsigned short* WsrcP_c; const unsigned short* VscP_p;
    unsigned short* xs_c; float *a_d_w, *a_s_c, *a_d_c;
    const float* x_a; int Na;
    const unsigned short* WlinP_a; const float* bla;
    const unsigned short* WsrcP_w; const unsigned short* VscP_a;
    unsigned short* xs_w; float* a_s_w;
    const int *src_w, *dst_w, *src_c, *dst_c;
    int Ew, Ec;
    const int *off2, *rank;
    int* srcu;
    int PB, AB;
};

__global__ __launch_bounds__(256) void mega(MegaArgs a) {
    __shared__ unsigned short xt[BM * LDST];
    int b = blockIdx.x;
    if (b < a.PB) {
        proj_body<2>(xt, b, a.x_p, a.Np, a.WlinP_p, a.blp, a.WsrcP_c, a.VscP_p,
                     a.xs_c, a.a_d_w, a.a_s_c, a.a_d_c);
        return;
    }
    if (b < a.PB + a.AB) {
        proj_body<1>(xt, b - a.PB, a.x_a, a.Na, a.WlinP_a, a.bla, a.WsrcP_w, a.VscP_a,
                     a.xs_w, a.a_s_w, nullptr, nullptr);
        return;
    }
    int i = (b - a.PB - a.AB) * 256 + threadIdx.x;
    int s, di;
    if (i < a.Ew) { s = a.src_w[i]; di = a.dst_w[i]; }
    else if (i < a.Ew + a.Ec) { int j = i - a.Ew; s = a.src_c[j]; di = a.Np + a.dst_c[j]; }
    else return;
    a.srcu[a.off2[di] + a.rank[i]] = s;
}

// ---------------------------------------------------------------------------
// Gather: self-loops handled analytically (sequential row reads); edge
// segments (real edges, padded to x4 with phantoms) processed interleaved.
// Output packed bf16 pairs.
// ---------------------------------------------------------------------------
__global__ __launch_bounds__(256) void gat_gather(
    const int* __restrict__ off, const int* __restrict__ srcu,
    const float* __restrict__ a_s_w, const float* __restrict__ a_d_w,
    const float* __restrict__ a_s_c, const float* __restrict__ a_d_c,
    const unsigned short* __restrict__ xs_w, const unsigned short* __restrict__ xs_c,
    uint32_t* __restrict__ gatb, int Np, int nselfw) {
    int l = threadIdx.x & 63;
    int d = blockIdx.x * 4 + (threadIdx.x >> 6);
    if (d >= Np) return;
    int h = l >> 3;
    int iw = off[d], w1 = off[d + 1];
    int ic = off[Np + d], c1 = off[Np + d + 1];
    float adw = a_d_w[(long)d * H + h];
    float adc = a_d_c[(long)d * H + h];
    float denw = 0.f, n0w = 0.f, n1w = 0.f;
    float denc = 0.f, n0c = 0.f, n1c = 0.f;
    // self-loop terms (block's own row: sequential, cache-friendly)
    if (d < nselfw) {
        float e = a_s_w[(long)d * H + h] + adw;
        e = e > 0.f ? e : NEG_SLOPE * e;
        float p = __expf(e);
        uint32_t v = *reinterpret_cast<const uint32_t*>(xs_w + (long)d * DHID + 2 * l);
        denw += p; n0w += p * bflo(v); n1w += p * bfhi(v);
    }
    {
        float e = a_s_c[(long)d * H + h] + adc;
        e = e > 0.f ? e : NEG_SLOPE * e;
        float p = __expf(e);
        uint32_t v = *reinterpret_cast<const uint32_t*>(xs_c + (long)d * DHID + 2 * l);
        denc += p; n0c += p * bflo(v); n1c += p * bfhi(v);
    }
    while (iw < w1 || ic < c1) {
        bool hw = iw < w1, hc = ic < c1;
        int4 sw, sc;
        if (hw) sw = *reinterpret_cast<const int4*>(srcu + iw);
        if (hc) sc = *reinterpret_cast<const int4*>(srcu + ic);
        float ew[4], ec[4];
        uint32_t vw[4], vc[4];
        if (hw) {
            ew[0] = a_s_w[(long)sw.x * H + h];
            ew[1] = a_s_w[(long)sw.y * H + h];
            ew[2] = a_s_w[(long)sw.z * H + h];
            ew[3] = a_s_w[(long)sw.w * H + h];
            vw[0] = *reinterpret_cast<const uint32_t*>(xs_w + (long)sw.x * DHID + 2 * l);
            vw[1] = *reinterpret_cast<const uint32_t*>(xs_w + (long)sw.y * DHID + 2 * l);
            vw[2] = *reinterpret_cast<const uint32_t*>(xs_w + (long)sw.z * DHID + 2 * l);
            vw[3] = *reinterpret_cast<const uint32_t*>(xs_w + (long)sw.w * DHID + 2 * l);
        }
        if (hc) {
            ec[0] = a_s_c[(long)sc.x * H + h];
            ec[1] = a_s_c[(long)sc.y * H + h];
            ec[2] = a_s_c[(long)sc.z * H + h];
            ec[3] = a_s_c[(long)sc.w * H + h];
            vc[0] = *reinterpret_cast<const uint32_t*>(xs_c + (long)sc.x * DHID + 2 * l);
            vc[1] = *reinterpret_cast<const uint32_t*>(xs_c + (long)sc.y * DHID + 2 * l);
            vc[2] = *reinterpret_cast<const uint32_t*>(xs_c + (long)sc.z * DHID + 2 * l);
            vc[3] = *reinterpret_cast<const uint32_t*>(xs_c + (long)sc.w * DHID + 2 * l);
        }
        if (hw) {
#pragma unroll
            for (int j = 0; j < 4; ++j) {
                float e = ew[j] + adw;
                e = e > 0.f ? e : NEG_SLOPE * e;
                float p = __expf(e);
                denw += p;
                n0w += p * bflo(vw[j]);
                n1w += p * bfhi(vw[j]);
            }
            iw += 4;
        }
        if (hc) {
#pragma unroll
            for (int j = 0; j < 4; ++j) {
                float e = ec[j] + adc;
                e = e > 0.f ? e : NEG_SLOPE * e;
                float p = __expf(e);
                denc += p;
                n0c += p * bflo(vc[j]);
                n1c += p * bfhi(vc[j]);
            }
            ic += 4;
        }
    }
    float rw = 1.f / (denw + 1e-16f);
    float rc = 1.f / (denc + 1e-16f);
    gatb[(long)d * 64 + l] = pack2bf(n0w * rw + n0c * rc, n1w * rw + n1c * rc);
}

// ---------------------------------------------------------------------------
// GraphNorm reduction over bf16-packed gat.
// ---------------------------------------------------------------------------
#define GN_ROWS 512
__global__ void gn_reduce(const uint32_t* __restrict__ gatb, const float* __restrict__ bsum,
                          float* __restrict__ colsum, float* __restrict__ colsumsq, int Np) {
    int t = threadIdx.x;
    int p = t & 63, ro = t >> 6;
    long r0 = (long)blockIdx.x * GN_ROWS + ro;
    long r1 = min((long)(blockIdx.x + 1) * GN_ROWS, (long)Np);
    float b0 = bsum[2 * p], b1 = bsum[2 * p + 1];
    float s1a = 0.f, s2a = 0.f, s1b = 0.f, s2b = 0.f;
    for (long r = r0; r < r1; r += 4) {
        uint32_t u = gatb[r * 64 + p];
        float x0 = bflo(u) + b0, x1 = bfhi(u) + b1;
        s1a += x0; s2a += x0 * x0;
        s1b += x1; s2b += x1 * x1;
    }
    atomAddF(colsum + 2 * p, s1a);
    atomAddF(colsumsq + 2 * p, s2a);
    atomAddF(colsum + 2 * p + 1, s1b);
    atomAddF(colsumsq + 2 * p + 1, s2b);
}

// ---------------------------------------------------------------------------
// K7: final_mfma (paper gnorm + @W2 + b2, bf16 gat input) ∥ author fill
// ---------------------------------------------------------------------------
__global__ __launch_bounds__(256) void final_fill(
    const uint32_t* __restrict__ gatb, const float* __restrict__ bsum,
    const float* __restrict__ colsum, const float* __restrict__ colsumsq,
    const float* __restrict__ gnw, const float* __restrict__ gnb,
    const float* __restrict__ gnm,
    const unsigned short* __restrict__ W2P, const float* __restrict__ b2,
    float* __restrict__ out, int Np, int FB,
    const float* __restrict__ row_a, float4* __restrict__ outa, long n4) {
    __shared__ unsigned short xt[BM * LDST];
    __shared__ float cscale[DHID], cshift[DHID];
    int b = blockIdx.x;
    int t = threadIdx.x;
    if (b >= FB) {
        long i = (long)(b - FB) * 256 + t;
        long stride = (long)(gridDim.x - FB) * 256;
        const float4* r4 = reinterpret_cast<const float4*>(row_a);
        for (; i < n4; i += stride) outa[i] = r4[i & 31];
        return;
    }
    int lane = t & 63, w = t >> 6;
    long row0 = (long)b * BM;
    if (t < DHID) {
        float invN = 1.f / (float)Np;
        float mu = colsum[t] * invN;
        float ms = gnm[t];
        float var = colsumsq[t] * invN - mu * mu * ms * (2.f - ms);
        float sc = gnw[t] * rsqrtf(var + GN_EPS);
        cscale[t] = sc;
        cshift[t] = (bsum[t] - ms * mu) * sc + gnb[t];
    }
    __syncthreads();
    for (int it = 0; it < 16; ++it) {
        int idx2 = t + it * 256;
        int r = idx2 >> 6, cp = idx2 & 63;
        long gr = row0 + r;
        float v0 = 0.f, v1 = 0.f;
        if (gr < Np) {
            uint32_t u = gatb[gr * 64 + cp];
            v0 = bflo(u) * cscale[2 * cp] + cshift[2 * cp];
            v1 = bfhi(u) * cscale[2 * cp + 1] + cshift[2 * cp + 1];
        }
        *reinterpret_cast<uint32_t*>(&xt[r * LDST + 2 * cp]) = pack2bf(v0, v1);
    }
    __syncthreads();
    int arow = w * 16 + (lane & 15);
    int koff = (lane >> 4) << 3;
    short8 af[4];
#pragma unroll
    for (int kk = 0; kk < 4; ++kk)
        af[kk] = *reinterpret_cast<const short8*>(&xt[arow * LDST + kk * 32 + koff]);
    const short8* Bw = reinterpret_cast<const short8*>(W2P);
    int orow = w * 16 + ((lane >> 4) << 2);
    int ccol = lane & 15;
#pragma unroll
    for (int nt = 0; nt < 8; ++nt) {
        f32x4 a = {0.f, 0.f, 0.f, 0.f};
#pragma unroll
        for (int kk = 0; kk < 4; ++kk)
            a = __builtin_amdgcn_mfma_f32_16x16x32_bf16(af[kk], Bw[(nt * 4 + kk) * 64 + lane], a, 0, 0, 0);
        float bb = b2[nt * 16 + ccol];
#pragma unroll
        for (int r = 0; r < 4; ++r) {
            long gr = row0 + orow + r;
            if (gr < Np) out[gr * DHID + nt * 16 + ccol] = a[r] + bb;
        }
    }
}

// ---------------------------------------------------------------------------
extern "C" void kernel_launch(void* const* d_in, const int* in_sizes, int n_in,
                              void* d_out, int out_size, void* d_ws, size_t ws_size,
                              hipStream_t stream) {
    const float* x_p   = (const float*)d_in[0];
    const float* x_a   = (const float*)d_in[1];
    const int*   e_w   = (const int*)d_in[2];
    const int*   e_c   = (const int*)d_in[3];
    const float* Wlp   = (const float*)d_in[4];
    const float* blp   = (const float*)d_in[5];
    const float* Wla   = (const float*)d_in[6];
    const float* bla   = (const float*)d_in[7];
    const float* Wsw   = (const float*)d_in[8];
    const float* Wdw   = (const float*)d_in[9];
    const float* asw   = (const float*)d_in[10];
    const float* adw   = (const float*)d_in[11];
    const float* bw    = (const float*)d_in[12];
    const float* Wsc   = (const float*)d_in[13];
    const float* Wdc   = (const float*)d_in[14];
    const float* asc   = (const float*)d_in[15];
    const float* adc   = (const float*)d_in[16];
    const float* bc    = (const float*)d_in[17];
    const float* gnw_p = (const float*)d_in[18];
    const float* gnb_p = (const float*)d_in[19];
    const float* gnm_p = (const float*)d_in[20];
    const float* gnb_a = (const float*)d_in[22];
    const float* W2p   = (const float*)d_in[24];
    const float* b2p   = (const float*)d_in[25];
    const float* W2a   = (const float*)d_in[26];
    const float* b2a   = (const float*)d_in[27];

    int Np = in_sizes[0] / DHID;
    int Na = in_sizes[1] / DHID;
    int Ew = in_sizes[2] / 2;
    int Ec = in_sizes[3] / 2;
    int nself_w = Na < Np ? Na : Np;
    int tot_edges = Ew + Ec;
    int maxTot = tot_edges + 6 * Np + 8;

    float* ws = (float*)d_ws;
    uint32_t* gatb = (uint32_t*)ws;                    // Np*64 (bf16 pairs)
    float* a_d_w = (float*)(gatb + (size_t)Np * 64);   // Np*8
    float* a_d_c = a_d_w + (size_t)Np * H;             // Np*8
    float* a_s_w = a_d_c + (size_t)Np * H;             // (Na+1)*8
    float* a_s_c = a_s_w + (size_t)(Na + 1) * H;       // (Np+1)*8
    float* bsum  = a_s_c + (size_t)(Np + 1) * H;       // 128
    float* row_a = bsum + DHID;                        // 128
    float* colsum   = row_a + DHID;                    // 128
    float* colsumsq = colsum + DHID;                   // 128
    int*   deg   = (int*)(colsumsq + DHID);            // 2*Np (memset)
    int* off_raw = deg + 2 * Np;                       // 2*Np
    int* off2    = off_raw + 2 * Np;                   // 2*Np + 1
    int* bs1     = off2 + 2 * Np + 1;                  // 512
    uintptr_t up = (uintptr_t)(bs1 + 512);
    up = (up + 15) & ~(uintptr_t)15;
    int* srcu = (int*)up;                              // maxTot
    int* rank = srcu + maxTot;                         // tot_edges
    unsigned short* xs_w = (unsigned short*)(rank + tot_edges);  // (Na+1)*128
    unsigned short* xs_c = xs_w + (size_t)(Na + 1) * DHID;       // (Np+1)*128
    up = (uintptr_t)(xs_c + (size_t)(Np + 1) * DHID);
    up = (up + 15) & ~(uintptr_t)15;
    unsigned short* WlinP_p = (unsigned short*)up;
    unsigned short* WsrcP_c = WlinP_p + 16384;
    unsigned short* WlinP_a = WsrcP_c + 16384;
    unsigned short* WsrcP_w = WlinP_a + 16384;
    unsigned short* W2P_p   = WsrcP_w + 16384;
    unsigned short* VscP_p  = W2P_p + 16384;
    unsigned short* VscP_a  = VscP_p + 4096;

    hipMemsetAsync(deg, 0, 2 * (size_t)Np * sizeof(int), stream);

    int HB = (tot_edges + 255) / 256;
    {
        PrepHist pa;
        pa.Wlp = Wlp; pa.Wsc = Wsc; pa.Wla = Wla; pa.Wsw = Wsw; pa.W2p = W2p;
        pa.Wdw = Wdw; pa.adw = adw; pa.asc_ = asc; pa.Wdc = Wdc; pa.adc_ = adc; pa.asw_ = asw;
        pa.WlinP_p = WlinP_p; pa.WsrcP_c = WsrcP_c; pa.WlinP_a = WlinP_a;
        pa.WsrcP_w = WsrcP_w; pa.W2P_p = W2P_p; pa.VscP_p = VscP_p; pa.VscP_a = VscP_a;
        pa.bw = bw; pa.bc = bc; pa.gnb_a = gnb_a; pa.W2a = W2a; pa.b2a = b2a;
        pa.bsum = bsum; pa.row_a = row_a; pa.colsum = colsum; pa.colsumsq = colsumsq;
        pa.xs_w_ph = xs_w + (size_t)Na * DHID;
        pa.xs_c_ph = xs_c + (size_t)Np * DHID;
        pa.as_w_ph = a_s_w + (size_t)Na * H;
        pa.as_c_ph = a_s_c + (size_t)Np * H;
        pa.dst_w = e_w + Ew; pa.dst_c = e_c + Ec;
        pa.deg = deg; pa.rank = rank;
        pa.Ew = Ew; pa.Ec = Ec;
        pa.Np = Np; pa.HB0 = 57;
        prep_hist<<<57 + HB, 256, 0, stream>>>(pa);
    }

    int n2 = 2 * Np;
    int nb = (n2 + SCAN_T * SCAN_I - 1) / (SCAN_T * SCAN_I);   // must be <= 256
    scan1<<<nb, SCAN_T, 0, stream>>>(deg, n2, off_raw, bs1);

    scan3_prefill<<<(maxTot + 255) / 256, 256, 0, stream>>>(
        off_raw, bs1, nb, n2, off2, Np, Na, maxTot, srcu);

    {
        MegaArgs ma;
        ma.x_p = x_p; ma.Np = Np; ma.WlinP_p = WlinP_p; ma.blp = blp;
        ma.WsrcP_c = WsrcP_c; ma.VscP_p = VscP_p;
        ma.xs_c = xs_c; ma.a_d_w = a_d_w; ma.a_s_c = a_s_c; ma.a_d_c = a_d_c;
        ma.x_a = x_a; ma.Na = Na; ma.WlinP_a = WlinP_a; ma.bla = bla;
        ma.WsrcP_w = WsrcP_w; ma.VscP_a = VscP_a;
        ma.xs_w = xs_w; ma.a_s_w = a_s_w;
        ma.src_w = e_w; ma.dst_w = e_w + Ew; ma.src_c = e_c; ma.dst_c = e_c + Ec;
        ma.Ew = Ew; ma.Ec = Ec;
        ma.off2 = off2; ma.rank = rank; ma.srcu = srcu;
        ma.PB = (Np + BM - 1) / BM;
        ma.AB = (Na + BM - 1) / BM;
        int SB = (tot_edges + 255) / 256;
        mega<<<ma.PB + ma.AB + SB, 256, 0, stream>>>(ma);
    }

    gat_gather<<<(Np + 3) / 4, 256, 0, stream>>>(off2, srcu,
                                                 a_s_w, a_d_w, a_s_c, a_d_c,
                                                 xs_w, xs_c, gatb, Np, nself_w);

    gn_reduce<<<(Np + GN_ROWS - 1) / GN_ROWS, 256, 0, stream>>>(gatb, bsum, colsum, colsumsq, Np);

    {
        int FB = (Np + BM - 1) / BM;
        long n4 = (long)Na * DHID / 4;
        final_fill<<<FB + 391, 256, 0, stream>>>(
            gatb, bsum, colsum, colsumsq, gnw_p, gnb_p, gnm_p, W2P_p, b2p,
            (float*)d_out, Np, FB,
            row_a, (float4*)((float*)d_out + (size_t)Np * DHID), n4);
    }
}

// Round 11
// 294.034 us; speedup vs baseline: 1.0578x; 1.0255x over previous
//
#include <hip/hip_runtime.h>
#include <cstdint>
#include <cstddef>

#define H 8
#define DHID 128
#define BM 64            // rows per MFMA block
#define LDST 136         // padded LDS row stride (bf16 elems)
#define NEG_SLOPE 0.2f
#define GN_EPS 1e-5f

#define SCAN_T 256
#define SCAN_I 4         // 1024 elements per scan block; requires 2*Np <= 256*1024

typedef __attribute__((ext_vector_type(8))) short short8;
typedef __attribute__((ext_vector_type(4))) float f32x4;

__device__ __forceinline__ void atomAddF(float* p, float v) {
    __hip_atomic_fetch_add(p, v, __ATOMIC_RELAXED, __HIP_MEMORY_SCOPE_AGENT);
}
__device__ __forceinline__ unsigned short f2bf(float f) {
    uint32_t u = __float_as_uint(f);
    uint32_t r = (u + 0x7FFFu + ((u >> 16) & 1u)) >> 16;
    return (unsigned short)r;
}
__device__ __forceinline__ uint32_t pack2bf(float lo, float hi) {
    return (uint32_t)f2bf(lo) | ((uint32_t)f2bf(hi) << 16);
}
__device__ __forceinline__ float bflo(uint32_t v) { return __uint_as_float(v << 16); }
__device__ __forceinline__ float bfhi(uint32_t v) { return __uint_as_float(v & 0xFFFF0000u); }

// ---------------------------------------------------------------------------
// K1: prep (pack weights -> MFMA B-frags, attention fold inline, misc init)
//     ∥ deg_hist (real edges only; MLP-4: 4 edges/thread, batched atomics).
// ---------------------------------------------------------------------------
struct PrepHist {
    const float *Wlp, *Wsc, *Wla, *Wsw, *W2p;
    const float *Wdw, *adw, *asc_, *Wdc, *adc_, *asw_;
    unsigned short *WlinP_p, *WsrcP_c, *WlinP_a, *WsrcP_w, *W2P_p, *VscP_p, *VscP_a;
    const float *bw, *bc, *gnb_a, *W2a, *b2a;
    float *bsum, *row_a, *colsum, *colsumsq;
    unsigned short *xs_w_ph, *xs_c_ph;
    float *as_w_ph, *as_c_ph;
    const int *dst_w, *dst_c;
    int *deg, *rank;
    int Ew, Ec, Np, HB0;
};

__global__ void prep_hist(PrepHist a) {
    int b = blockIdx.x, t = threadIdx.x;
    if (b >= a.HB0) {
        int base = (b - a.HB0) * 1024 + t;
        int E = a.Ew + a.Ec;
        int dd[4];
        bool val[4];
#pragma unroll
        for (int j = 0; j < 4; ++j) {
            int i = base + j * 256;
            val[j] = i < E;
            dd[j] = 0;
            if (val[j]) dd[j] = (i < a.Ew) ? a.dst_w[i] : (a.Np + a.dst_c[i - a.Ew]);
        }
        int rk[4];
#pragma unroll
        for (int j = 0; j < 4; ++j)
            if (val[j]) rk[j] = atomicAdd(&a.deg[dd[j]], 1);
#pragma unroll
        for (int j = 0; j < 4; ++j)
            if (val[j]) a.rank[base + j * 256] = rk[j];
        return;
    }
    if (b == 56) {
        if (t < 128) {
            a.bsum[t] = a.bw[t] + a.bc[t];
            float acc = a.b2a[t];
            for (int k = 0; k < DHID; ++k) acc += a.gnb_a[k] * a.W2a[k * DHID + t];
            a.row_a[t] = acc;
            a.colsum[t] = 0.f;
            a.colsumsq[t] = 0.f;
            a.xs_w_ph[t] = 0;
            a.xs_c_ph[t] = 0;
        } else if (t < 136) a.as_w_ph[t - 128] = -1e30f;
        else if (t < 144) a.as_c_ph[t - 136] = -1e30f;
        return;
    }
    int j = b >> 3;
    int idx = (b & 7) * 256 + t;
    int lane = idx & 63, kk = (idx >> 6) & 3, nt = idx >> 8;
    int col = nt * 16 + (lane & 15);
    int k0 = kk * 32 + ((lane >> 4) << 3);
    if (j < 5) {
        const float* W = j == 0 ? a.Wlp : j == 1 ? a.Wsc : j == 2 ? a.Wla : j == 3 ? a.Wsw : a.W2p;
        unsigned short* out = j == 0 ? a.WlinP_p : j == 1 ? a.WsrcP_c : j == 2 ? a.WlinP_a
                              : j == 3 ? a.WsrcP_w : a.W2P_p;
        for (int i = 0; i < 8; ++i) out[idx * 8 + i] = f2bf(W[(k0 + i) * DHID + col]);
    } else if (j == 5) {
        if (idx >= 2 * 256) return;
        const float *W = nullptr, *A = nullptr;
        int h = col & 7;
        if (col < 24) {
            int which = col >> 3;
            W = which == 0 ? a.Wdw : which == 1 ? a.Wsc : a.Wdc;
            A = which == 0 ? a.adw : which == 1 ? a.asc_ : a.adc_;
        }
        for (int i = 0; i < 8; ++i) {
            float v = 0.f;
            if (W)
                for (int c = 0; c < 16; ++c) v += W[(k0 + i) * DHID + h * 16 + c] * A[h * 16 + c];
            a.VscP_p[idx * 8 + i] = f2bf(v);
        }
    } else {
        if (idx >= 256) return;
        int h = col & 7;
        for (int i = 0; i < 8; ++i) {
            float v = 0.f;
            if (col < 8)
                for (int c = 0; c < 16; ++c)
                    v += a.Wsw[(k0 + i) * DHID + h * 16 + c] * a.asw_[h * 16 + c];
            a.VscP_a[idx * 8 + i] = f2bf(v);
        }
    }
}

// ---------------------------------------------------------------------------
// Exclusive scan pass 1 (per-block) with pad-to-4; bsums collects block totals.
// ---------------------------------------------------------------------------
__global__ void scan1(const int* __restrict__ in, int n, int* __restrict__ out,
                      int* __restrict__ bsums) {
    __shared__ int sh[SCAN_T];
    int t = threadIdx.x;
    long base = (long)blockIdx.x * SCAN_T * SCAN_I;
    int v[SCAN_I];
    int s = 0;
#pragma unroll
    for (int j = 0; j < SCAN_I; ++j) {
        long idx = base + (long)t * SCAN_I + j;
        int x = (idx < n) ? in[idx] : 0;
        x = (x + 3) & ~3;               // pad each segment to multiple of 4
        v[j] = x;
        s += x;
    }
    sh[t] = s;
    __syncthreads();
    for (int off = 1; off < SCAN_T; off <<= 1) {
        int x = (t >= off) ? sh[t - off] : 0;
        __syncthreads();
        sh[t] += x;
        __syncthreads();
    }
    int run = sh[t] - s;
#pragma unroll
    for (int j = 0; j < SCAN_I; ++j) {
        long idx = base + (long)t * SCAN_I + j;
        if (idx < n) out[idx] = run;
        run += v[j];
    }
    if (t == SCAN_T - 1) bsums[blockIdx.x] = sh[SCAN_T - 1];
}

// ---------------------------------------------------------------------------
// scan3_prefill: scans bs1 (nb <= 256) in-LDS, then off2 = off_raw + prefix,
// writes sentinel off2[n2], and prefills srcu with phantom ids.
// ---------------------------------------------------------------------------
__global__ void scan3_prefill(const int* __restrict__ off_raw, const int* __restrict__ bs1,
                              int nb, int n2, int* __restrict__ off2,
                              int Np, int Na, int maxTot, int* __restrict__ srcu) {
    __shared__ int pf[SCAN_T];      // inclusive prefix of bs1
    int t = threadIdx.x;
    pf[t] = (t < nb) ? bs1[t] : 0;
    __syncthreads();
    for (int off = 1; off < SCAN_T; off <<= 1) {
        int x = (t >= off) ? pf[t - off] : 0;
        __syncthreads();
        pf[t] += x;
        __syncthreads();
    }
    int i = blockIdx.x * 256 + t;
    if (i < n2) {
        int g = i >> 10;
        off2[i] = off_raw[i] + (g ? pf[g - 1] : 0);
    }
    if (blockIdx.x == 0 && t == 0) off2[n2] = pf[nb - 1];
    int gm = Np >> 10;
    int mid = off_raw[Np] + (gm ? pf[gm - 1] : 0);
    long stride = (long)gridDim.x * 256;
    for (long k = i; k < maxTot; k += stride) srcu[k] = (k < (long)mid) ? Na : Np;
}

// ---------------------------------------------------------------------------
// MFMA projection body (paper NSC=2 / author NSC=1), LDS-staged x (coalesced).
// ---------------------------------------------------------------------------
template <int NSC>
__device__ void proj_body(unsigned short* xt, int bid,
                          const float* __restrict__ x, int nrows,
                          const unsigned short* __restrict__ WlinP, const float* __restrict__ blin,
                          const unsigned short* __restrict__ WsrcP,
                          const unsigned short* __restrict__ VscP,
                          unsigned short* __restrict__ xs,
                          float* __restrict__ a0, float* __restrict__ a1, float* __restrict__ a2) {
    int t = threadIdx.x;
    int lane = t & 63, w = t >> 6;
    long row0 = (long)bid * BM;
    for (int it = 0; it < 16; ++it) {
        int idx2 = t + it * 256;
        int r = idx2 >> 6, cp = idx2 & 63;
        long gr = row0 + r;
        float v0 = 0.f, v1 = 0.f;
        if (gr < nrows) { v0 = x[gr * DHID + 2 * cp]; v1 = x[gr * DHID + 2 * cp + 1]; }
        *reinterpret_cast<uint32_t*>(&xt[r * LDST + 2 * cp]) = pack2bf(v0, v1);
    }
    __syncthreads();
    int arow = w * 16 + (lane & 15);
    int koff = (lane >> 4) << 3;
    short8 af[4];
#pragma unroll
    for (int kk = 0; kk < 4; ++kk)
        af[kk] = *reinterpret_cast<const short8*>(&xt[arow * LDST + kk * 32 + koff]);
    const short8* Bl = reinterpret_cast<const short8*>(WlinP);
    f32x4 acc[8];
#pragma unroll
    for (int nt = 0; nt < 8; ++nt) {
        f32x4 a = {0.f, 0.f, 0.f, 0.f};
#pragma unroll
        for (int kk = 0; kk < 4; ++kk)
            a = __builtin_amdgcn_mfma_f32_16x16x32_bf16(af[kk], Bl[(nt * 4 + kk) * 64 + lane], a, 0, 0, 0);
        acc[nt] = a;
    }
    __syncthreads();
    int orow = w * 16 + ((lane >> 4) << 2);
    int ccol = lane & 15;
#pragma unroll
    for (int nt = 0; nt < 8; ++nt) {
        float b = blin[nt * 16 + ccol];
#pragma unroll
        for (int r = 0; r < 4; ++r) {
            float e = fmaxf(acc[nt][r] + b, 0.f);
            xt[(orow + r) * LDST + nt * 16 + ccol] = f2bf(e);
        }
    }
    __syncthreads();
#pragma unroll
    for (int kk = 0; kk < 4; ++kk)
        af[kk] = *reinterpret_cast<const short8*>(&xt[arow * LDST + kk * 32 + koff]);
    const short8* Bs = reinterpret_cast<const short8*>(WsrcP);
#pragma unroll
    for (int nt = 0; nt < 8; ++nt) {
        f32x4 a = {0.f, 0.f, 0.f, 0.f};
#pragma unroll
        for (int kk = 0; kk < 4; ++kk)
            a = __builtin_amdgcn_mfma_f32_16x16x32_bf16(af[kk], Bs[(nt * 4 + kk) * 64 + lane], a, 0, 0, 0);
        acc[nt] = a;
    }
    const short8* Bv = reinterpret_cast<const short8*>(VscP);
    f32x4 sacc0 = {0.f, 0.f, 0.f, 0.f}, sacc1 = {0.f, 0.f, 0.f, 0.f};
#pragma unroll
    for (int kk = 0; kk < 4; ++kk)
        sacc0 = __builtin_amdgcn_mfma_f32_16x16x32_bf16(af[kk], Bv[kk * 64 + lane], sacc0, 0, 0, 0);
    if (NSC > 1) {
#pragma unroll
        for (int kk = 0; kk < 4; ++kk)
            sacc1 = __builtin_amdgcn_mfma_f32_16x16x32_bf16(af[kk], Bv[(4 + kk) * 64 + lane], sacc1, 0, 0, 0);
    }
#pragma unroll
    for (int nt = 0; nt < 8; ++nt) {
#pragma unroll
        for (int r = 0; r < 4; ++r) {
            long gr = row0 + orow + r;
            if (gr < nrows) xs[gr * DHID + nt * 16 + ccol] = f2bf(acc[nt][r]);
        }
    }
#pragma unroll
    for (int st = 0; st < NSC; ++st) {
        int scol = st * 16 + ccol;
        int h = scol & 7, which = scol >> 3;
        float* ap = which == 0 ? a0 : which == 1 ? a1 : which == 2 ? a2 : nullptr;
        if (ap) {
            f32x4 s = st == 0 ? sacc0 : sacc1;
#pragma unroll
            for (int r = 0; r < 4; ++r) {
                long gr = row0 + orow + r;
                if (gr < nrows) ap[gr * H + h] = s[r];
            }
        }
    }
}

// ---------------------------------------------------------------------------
// K4 MEGA: proj_paper, proj_author, then atomic-free scatter (MLP-4).
// ---------------------------------------------------------------------------
struct MegaArgs {
    const float* x_p; int Np;
    const unsigned short* WlinP_p; const float* blp;
    const unsigned short* WsrcP_c; const unsigned short* VscP_p;
    unsigned short* xs_c; float *a_d_w, *a_s_c, *a_d_c;
    const float* x_a; int Na;
    const unsigned short* WlinP_a; const float* bla;
    const unsigned short* WsrcP_w; const unsigned short* VscP_a;
    unsigned short* xs_w; float* a_s_w;
    const int *src_w, *dst_w, *src_c, *dst_c;
    int Ew, Ec;
    const int *off2, *rank;
    int* srcu;
    int PB, AB;
};

__global__ __launch_bounds__(256) void mega(MegaArgs a) {
    __shared__ unsigned short xt[BM * LDST];
    int b = blockIdx.x;
    if (b < a.PB) {
        proj_body<2>(xt, b, a.x_p, a.Np, a.WlinP_p, a.blp, a.WsrcP_c, a.VscP_p,
                     a.xs_c, a.a_d_w, a.a_s_c, a.a_d_c);
        return;
    }
    if (b < a.PB + a.AB) {
        proj_body<1>(xt, b - a.PB, a.x_a, a.Na, a.WlinP_a, a.bla, a.WsrcP_w, a.VscP_a,
                     a.xs_w, a.a_s_w, nullptr, nullptr);
        return;
    }
    // ---- scatter, MLP-4: 4 edges/thread, batched random reads then stores ----
    int base = (b - a.PB - a.AB) * 1024 + threadIdx.x;
    int E = a.Ew + a.Ec;
    int s[4], di[4], rk[4];
    bool val[4];
#pragma unroll
    for (int j = 0; j < 4; ++j) {
        int i = base + j * 256;
        val[j] = i < E;
        s[j] = di[j] = rk[j] = 0;
        if (val[j]) {
            if (i < a.Ew) { s[j] = a.src_w[i]; di[j] = a.dst_w[i]; }
            else { int q = i - a.Ew; s[j] = a.src_c[q]; di[j] = a.Np + a.dst_c[q]; }
            rk[j] = a.rank[i];
        }
    }
    int pos[4];
#pragma unroll
    for (int j = 0; j < 4; ++j)
        if (val[j]) pos[j] = a.off2[di[j]] + rk[j];
#pragma unroll
    for (int j = 0; j < 4; ++j)
        if (val[j]) a.srcu[pos[j]] = s[j];
}

// ---------------------------------------------------------------------------
// Gather ∥ author broadcast-fill (fill blocks dispatched first: streaming
// writes overlap under gather's latency-bound phase).
// Self-loops analytic; edge segments padded x4 with phantoms; bf16 output.
// ---------------------------------------------------------------------------
#define FILLB 391
__global__ __launch_bounds__(256) void gat_gather(
    const int* __restrict__ off, const int* __restrict__ srcu,
    const float* __restrict__ a_s_w, const float* __restrict__ a_d_w,
    const float* __restrict__ a_s_c, const float* __restrict__ a_d_c,
    const unsigned short* __restrict__ xs_w, const unsigned short* __restrict__ xs_c,
    uint32_t* __restrict__ gatb, int Np, int nselfw,
    const float* __restrict__ row_a, float4* __restrict__ outa, long n4) {
    if (blockIdx.x < FILLB) {
        long i = (long)blockIdx.x * 256 + threadIdx.x;
        long stride = (long)FILLB * 256;
        const float4* r4 = reinterpret_cast<const float4*>(row_a);
        for (; i < n4; i += stride) outa[i] = r4[i & 31];
        return;
    }
    int l = threadIdx.x & 63;
    int d = (blockIdx.x - FILLB) * 4 + (threadIdx.x >> 6);
    if (d >= Np) return;
    int h = l >> 3;
    int iw = off[d], w1 = off[d + 1];
    int ic = off[Np + d], c1 = off[Np + d + 1];
    float adw = a_d_w[(long)d * H + h];
    float adc = a_d_c[(long)d * H + h];
    float denw = 0.f, n0w = 0.f, n1w = 0.f;
    float denc = 0.f, n0c = 0.f, n1c = 0.f;
    if (d < nselfw) {
        float e = a_s_w[(long)d * H + h] + adw;
        e = e > 0.f ? e : NEG_SLOPE * e;
        float p = __expf(e);
        uint32_t v = *reinterpret_cast<const uint32_t*>(xs_w + (long)d * DHID + 2 * l);
        denw += p; n0w += p * bflo(v); n1w += p * bfhi(v);
    }
    {
        float e = a_s_c[(long)d * H + h] + adc;
        e = e > 0.f ? e : NEG_SLOPE * e;
        float p = __expf(e);
        uint32_t v = *reinterpret_cast<const uint32_t*>(xs_c + (long)d * DHID + 2 * l);
        denc += p; n0c += p * bflo(v); n1c += p * bfhi(v);
    }
    while (iw < w1 || ic < c1) {
        bool hw = iw < w1, hc = ic < c1;
        int4 sw, sc;
        if (hw) sw = *reinterpret_cast<const int4*>(srcu + iw);
        if (hc) sc = *reinterpret_cast<const int4*>(srcu + ic);
        float ew[4], ec[4];
        uint32_t vw[4], vc[4];
        if (hw) {
            ew[0] = a_s_w[(long)sw.x * H + h];
            ew[1] = a_s_w[(long)sw.y * H + h];
            ew[2] = a_s_w[(long)sw.z * H + h];
            ew[3] = a_s_w[(long)sw.w * H + h];
            vw[0] = *reinterpret_cast<const uint32_t*>(xs_w + (long)sw.x * DHID + 2 * l);
            vw[1] = *reinterpret_cast<const uint32_t*>(xs_w + (long)sw.y * DHID + 2 * l);
            vw[2] = *reinterpret_cast<const uint32_t*>(xs_w + (long)sw.z * DHID + 2 * l);
            vw[3] = *reinterpret_cast<const uint32_t*>(xs_w + (long)sw.w * DHID + 2 * l);
        }
        if (hc) {
            ec[0] = a_s_c[(long)sc.x * H + h];
            ec[1] = a_s_c[(long)sc.y * H + h];
            ec[2] = a_s_c[(long)sc.z * H + h];
            ec[3] = a_s_c[(long)sc.w * H + h];
            vc[0] = *reinterpret_cast<const uint32_t*>(xs_c + (long)sc.x * DHID + 2 * l);
            vc[1] = *reinterpret_cast<const uint32_t*>(xs_c + (long)sc.y * DHID + 2 * l);
            vc[2] = *reinterpret_cast<const uint32_t*>(xs_c + (long)sc.z * DHID + 2 * l);
            vc[3] = *reinterpret_cast<const uint32_t*>(xs_c + (long)sc.w * DHID + 2 * l);
        }
        if (hw) {
#pragma unroll
            for (int j = 0; j < 4; ++j) {
                float e = ew[j] + adw;
                e = e > 0.f ? e : NEG_SLOPE * e;
                float p = __expf(e);
                denw += p;
                n0w += p * bflo(vw[j]);
                n1w += p * bfhi(vw[j]);
            }
            iw += 4;
        }
        if (hc) {
#pragma unroll
            for (int j = 0; j < 4; ++j) {
                float e = ec[j] + adc;
                e = e > 0.f ? e : NEG_SLOPE * e;
                float p = __expf(e);
                denc += p;
                n0c += p * bflo(vc[j]);
                n1c += p * bfhi(vc[j]);
            }
            ic += 4;
        }
    }
    float rw = 1.f / (denw + 1e-16f);
    float rc = 1.f / (denc + 1e-16f);
    gatb[(long)d * 64 + l] = pack2bf(n0w * rw + n0c * rc, n1w * rw + n1c * rc);
}

// ---------------------------------------------------------------------------
// GraphNorm reduction over bf16-packed gat.
// ---------------------------------------------------------------------------
#define GN_ROWS 512
__global__ void gn_reduce(const uint32_t* __restrict__ gatb, const float* __restrict__ bsum,
                          float* __restrict__ colsum, float* __restrict__ colsumsq, int Np) {
    int t = threadIdx.x;
    int p = t & 63, ro = t >> 6;
    long r0 = (long)blockIdx.x * GN_ROWS + ro;
    long r1 = min((long)(blockIdx.x + 1) * GN_ROWS, (long)Np);
    float b0 = bsum[2 * p], b1 = bsum[2 * p + 1];
    float s1a = 0.f, s2a = 0.f, s1b = 0.f, s2b = 0.f;
    for (long r = r0; r < r1; r += 4) {
        uint32_t u = gatb[r * 64 + p];
        float x0 = bflo(u) + b0, x1 = bfhi(u) + b1;
        s1a += x0; s2a += x0 * x0;
        s1b += x1; s2b += x1 * x1;
    }
    atomAddF(colsum + 2 * p, s1a);
    atomAddF(colsumsq + 2 * p, s2a);
    atomAddF(colsum + 2 * p + 1, s1b);
    atomAddF(colsumsq + 2 * p + 1, s2b);
}

// ---------------------------------------------------------------------------
// K7: final_mfma (paper gnorm + @W2 + b2, bf16 gat input)
// ---------------------------------------------------------------------------
__global__ __launch_bounds__(256) void final_fill(
    const uint32_t* __restrict__ gatb, const float* __restrict__ bsum,
    const float* __restrict__ colsum, const float* __restrict__ colsumsq,
    const float* __restrict__ gnw, const float* __restrict__ gnb,
    const float* __restrict__ gnm,
    const unsigned short* __restrict__ W2P, const float* __restrict__ b2,
    float* __restrict__ out, int Np) {
    __shared__ unsigned short xt[BM * LDST];
    __shared__ float cscale[DHID], cshift[DHID];
    int b = blockIdx.x;
    int t = threadIdx.x;
    int lane = t & 63, w = t >> 6;
    long row0 = (long)b * BM;
    if (t < DHID) {
        float invN = 1.f / (float)Np;
        float mu = colsum[t] * invN;
        float ms = gnm[t];
        float var = colsumsq[t] * invN - mu * mu * ms * (2.f - ms);
        float sc = gnw[t] * rsqrtf(var + GN_EPS);
        cscale[t] = sc;
        cshift[t] = (bsum[t] - ms * mu) * sc + gnb[t];
    }
    __syncthreads();
    for (int it = 0; it < 16; ++it) {
        int idx2 = t + it * 256;
        int r = idx2 >> 6, cp = idx2 & 63;
        long gr = row0 + r;
        float v0 = 0.f, v1 = 0.f;
        if (gr < Np) {
            uint32_t u = gatb[gr * 64 + cp];
            v0 = bflo(u) * cscale[2 * cp] + cshift[2 * cp];
            v1 = bfhi(u) * cscale[2 * cp + 1] + cshift[2 * cp + 1];
        }
        *reinterpret_cast<uint32_t*>(&xt[r * LDST + 2 * cp]) = pack2bf(v0, v1);
    }
    __syncthreads();
    int arow = w * 16 + (lane & 15);
    int koff = (lane >> 4) << 3;
    short8 af[4];
#pragma unroll
    for (int kk = 0; kk < 4; ++kk)
        af[kk] = *reinterpret_cast<const short8*>(&xt[arow * LDST + kk * 32 + koff]);
    const short8* Bw = reinterpret_cast<const short8*>(W2P);
    int orow = w * 16 + ((lane >> 4) << 2);
    int ccol = lane & 15;
#pragma unroll
    for (int nt = 0; nt < 8; ++nt) {
        f32x4 a = {0.f, 0.f, 0.f, 0.f};
#pragma unroll
        for (int kk = 0; kk < 4; ++kk)
            a = __builtin_amdgcn_mfma_f32_16x16x32_bf16(af[kk], Bw[(nt * 4 + kk) * 64 + lane], a, 0, 0, 0);
        float bb = b2[nt * 16 + ccol];
#pragma unroll
        for (int r = 0; r < 4; ++r) {
            long gr = row0 + orow + r;
            if (gr < Np) out[gr * DHID + nt * 16 + ccol] = a[r] + bb;
        }
    }
}

// ---------------------------------------------------------------------------
extern "C" void kernel_launch(void* const* d_in, const int* in_sizes, int n_in,
                              void* d_out, int out_size, void* d_ws, size_t ws_size,
                              hipStream_t stream) {
    const float* x_p   = (const float*)d_in[0];
    const float* x_a   = (const float*)d_in[1];
    const int*   e_w   = (const int*)d_in[2];
    const int*   e_c   = (const int*)d_in[3];
    const float* Wlp   = (const float*)d_in[4];
    const float* blp   = (const float*)d_in[5];
    const float* Wla   = (const float*)d_in[6];
    const float* bla   = (const float*)d_in[7];
    const float* Wsw   = (const float*)d_in[8];
    const float* Wdw   = (const float*)d_in[9];
    const float* asw   = (const float*)d_in[10];
    const float* adw   = (const float*)d_in[11];
    const float* bw    = (const float*)d_in[12];
    const float* Wsc   = (const float*)d_in[13];
    const float* Wdc   = (const float*)d_in[14];
    const float* asc   = (const float*)d_in[15];
    const float* adc   = (const float*)d_in[16];
    const float* bc    = (const float*)d_in[17];
    const float* gnw_p = (const float*)d_in[18];
    const float* gnb_p = (const float*)d_in[19];
    const float* gnm_p = (const float*)d_in[20];
    const float* gnb_a = (const float*)d_in[22];
    const float* W2p   = (const float*)d_in[24];
    const float* b2p   = (const float*)d_in[25];
    const float* W2a   = (const float*)d_in[26];
    const float* b2a   = (const float*)d_in[27];

    int Np = in_sizes[0] / DHID;
    int Na = in_sizes[1] / DHID;
    int Ew = in_sizes[2] / 2;
    int Ec = in_sizes[3] / 2;
    int nself_w = Na < Np ? Na : Np;
    int tot_edges = Ew + Ec;
    int maxTot = tot_edges + 6 * Np + 8;

    float* ws = (float*)d_ws;
    uint32_t* gatb = (uint32_t*)ws;                    // Np*64 (bf16 pairs)
    float* a_d_w = (float*)(gatb + (size_t)Np * 64);   // Np*8
    float* a_d_c = a_d_w + (size_t)Np * H;             // Np*8
    float* a_s_w = a_d_c + (size_t)Np * H;             // (Na+1)*8
    float* a_s_c = a_s_w + (size_t)(Na + 1) * H;       // (Np+1)*8
    float* bsum  = a_s_c + (size_t)(Np + 1) * H;       // 128
    float* row_a = bsum + DHID;                        // 128
    float* colsum   = row_a + DHID;                    // 128
    float* colsumsq = colsum + DHID;                   // 128
    int*   deg   = (int*)(colsumsq + DHID);            // 2*Np (memset)
    int* off_raw = deg + 2 * Np;                       // 2*Np
    int* off2    = off_raw + 2 * Np;                   // 2*Np + 1
    int* bs1     = off2 + 2 * Np + 1;                  // 512
    uintptr_t up = (uintptr_t)(bs1 + 512);
    up = (up + 15) & ~(uintptr_t)15;
    int* srcu = (int*)up;                              // maxTot
    int* rank = srcu + maxTot;                         // tot_edges
    unsigned short* xs_w = (unsigned short*)(rank + tot_edges);  // (Na+1)*128
    unsigned short* xs_c = xs_w + (size_t)(Na + 1) * DHID;       // (Np+1)*128
    up = (uintptr_t)(xs_c + (size_t)(Np + 1) * DHID);
    up = (up + 15) & ~(uintptr_t)15;
    unsigned short* WlinP_p = (unsigned short*)up;
    unsigned short* WsrcP_c = WlinP_p + 16384;
    unsigned short* WlinP_a = WsrcP_c + 16384;
    unsigned short* WsrcP_w = WlinP_a + 16384;
    unsigned short* W2P_p   = WsrcP_w + 16384;
    unsigned short* VscP_p  = W2P_p + 16384;
    unsigned short* VscP_a  = VscP_p + 4096;

    hipMemsetAsync(deg, 0, 2 * (size_t)Np * sizeof(int), stream);

    int HB = (tot_edges + 1023) / 1024;      // MLP-4: 4 edges/thread
    {
        PrepHist pa;
        pa.Wlp = Wlp; pa.Wsc = Wsc; pa.Wla = Wla; pa.Wsw = Wsw; pa.W2p = W2p;
        pa.Wdw = Wdw; pa.adw = adw; pa.asc_ = asc; pa.Wdc = Wdc; pa.adc_ = adc; pa.asw_ = asw;
        pa.WlinP_p = WlinP_p; pa.WsrcP_c = WsrcP_c; pa.WlinP_a = WlinP_a;
        pa.WsrcP_w = WsrcP_w; pa.W2P_p = W2P_p; pa.VscP_p = VscP_p; pa.VscP_a = VscP_a;
        pa.bw = bw; pa.bc = bc; pa.gnb_a = gnb_a; pa.W2a = W2a; pa.b2a = b2a;
        pa.bsum = bsum; pa.row_a = row_a; pa.colsum = colsum; pa.colsumsq = colsumsq;
        pa.xs_w_ph = xs_w + (size_t)Na * DHID;
        pa.xs_c_ph = xs_c + (size_t)Np * DHID;
        pa.as_w_ph = a_s_w + (size_t)Na * H;
        pa.as_c_ph = a_s_c + (size_t)Np * H;
        pa.dst_w = e_w + Ew; pa.dst_c = e_c + Ec;
        pa.deg = deg; pa.rank = rank;
        pa.Ew = Ew; pa.Ec = Ec;
        pa.Np = Np; pa.HB0 = 57;
        prep_hist<<<57 + HB, 256, 0, stream>>>(pa);
    }

    int n2 = 2 * Np;
    int nb = (n2 + SCAN_T * SCAN_I - 1) / (SCAN_T * SCAN_I);   // must be <= 256
    scan1<<<nb, SCAN_T, 0, stream>>>(deg, n2, off_raw, bs1);

    scan3_prefill<<<(maxTot + 255) / 256, 256, 0, stream>>>(
        off_raw, bs1, nb, n2, off2, Np, Na, maxTot, srcu);

    {
        MegaArgs ma;
        ma.x_p = x_p; ma.Np = Np; ma.WlinP_p = WlinP_p; ma.blp = blp;
        ma.WsrcP_c = WsrcP_c; ma.VscP_p = VscP_p;
        ma.xs_c = xs_c; ma.a_d_w = a_d_w; ma.a_s_c = a_s_c; ma.a_d_c = a_d_c;
        ma.x_a = x_a; ma.Na = Na; ma.WlinP_a = WlinP_a; ma.bla = bla;
        ma.WsrcP_w = WsrcP_w; ma.VscP_a = VscP_a;
        ma.xs_w = xs_w; ma.a_s_w = a_s_w;
        ma.src_w = e_w; ma.dst_w = e_w + Ew; ma.src_c = e_c; ma.dst_c = e_c + Ec;
        ma.Ew = Ew; ma.Ec = Ec;
        ma.off2 = off2; ma.rank = rank; ma.srcu = srcu;
        ma.PB = (Np + BM - 1) / BM;
        ma.AB = (Na + BM - 1) / BM;
        int SB = (tot_edges + 1023) / 1024;  // MLP-4 scatter
        mega<<<ma.PB + ma.AB + SB, 256, 0, stream>>>(ma);
    }

    {
        long n4 = (long)Na * DHID / 4;
        gat_gather<<<FILLB + (Np + 3) / 4, 256, 0, stream>>>(
            off2, srcu, a_s_w, a_d_w, a_s_c, a_d_c, xs_w, xs_c, gatb, Np, nself_w,
            row_a, (float4*)((float*)d_out + (size_t)Np * DHID), n4);
    }

    gn_reduce<<<(Np + GN_ROWS - 1) / GN_ROWS, 256, 0, stream>>>(gatb, bsum, colsum, colsumsq, Np);

    final_fill<<<(Np + BM - 1) / BM, 256, 0, stream>>>(
        gatb, bsum, colsum, colsumsq, gnw_p, gnb_p, gnm_p, W2P_p, b2p,
        (float*)d_out, Np);
}